// Round 3
// baseline (1767.811 us; speedup 1.0000x reference)
//
#include <hip/hip_runtime.h>
#include <hip/hip_bf16.h>

typedef _Float16 half8 __attribute__((ext_vector_type(8)));
typedef float floatx4 __attribute__((ext_vector_type(4)));

#define MFMA_F16(a, b, c) __builtin_amdgcn_mfma_f32_16x16x32_f16((a), (b), (c), 0, 0, 0)

// ---------------------------------------------------------------------------
// fused prep: 13 f32->f16 (optional transpose, scale) jobs in one launch.
// ---------------------------------------------------------------------------
struct PrepJobs {
  const float* src[13];
  _Float16* dst[13];
  int In[13], Out[13], elems[13], doT[13];
  float scale[13];
};

__global__ void prep_all_kernel(PrepJobs J) {
  int j = blockIdx.y;
  int idx = blockIdx.x * 256 + threadIdx.x;
  if (idx >= J.elems[j]) return;
  float v;
  if (J.doT[j]) { int o = idx / J.In[j], i = idx - o * J.In[j]; v = J.src[j][i * J.Out[j] + o]; }
  else          { v = J.src[j][idx]; }
  J.dst[j][idx] = (_Float16)(v * J.scale[j]);
}

__global__ void init_ctr_kernel(int* __restrict__ ctr) {
  if (threadIdx.x < 16) ctr[threadIdx.x] = 0;
}

// ---------------------------------------------------------------------------
// phase 1: fused LN + dual GEMM.  grid (1536, 2), 256 threads. (unchanged)
// ---------------------------------------------------------------------------
__global__ __launch_bounds__(256) void gemm_kv_kernel(
    const float* __restrict__ x, const float* __restrict__ lnw_g,
    const float* __restrict__ lnb_g, const _Float16* __restrict__ WT,
    _Float16* __restrict__ kout, _Float16* __restrict__ vTout) {
  __shared__ union {
    struct { _Float16 A[128][72]; _Float16 B[128][72]; } s;
    _Float16 C[128][136];
  } u;
  __shared__ float s_mean[128], s_rstd[128], s_red[256][2], s_lnw[256], s_lnb[256];

  const int tid = threadIdx.x;
  const int bx = blockIdx.x, y = blockIdx.y;
  const size_t r0 = (size_t)bx * 128;
  const int w = tid >> 6, lane = tid & 63, quad = lane >> 4, l15 = lane & 15;

  s_lnw[tid] = lnw_g[tid];
  s_lnb[tid] = lnb_g[tid];
  {
    int row = tid >> 1, half = tid & 1;
    const float* p = x + (r0 + row) * 256 + half * 128;
    float s = 0.f, sq = 0.f;
    for (int i = 0; i < 32; i++) {
      float4 d = ((const float4*)p)[i];
      s += d.x + d.y + d.z + d.w;
      sq += d.x * d.x + d.y * d.y + d.z * d.z + d.w * d.w;
    }
    s_red[tid][0] = s; s_red[tid][1] = sq;
  }
  __syncthreads();
  if (tid < 128) {
    float s  = s_red[2 * tid][0] + s_red[2 * tid + 1][0];
    float sq = s_red[2 * tid][1] + s_red[2 * tid + 1][1];
    float m = s * (1.f / 256.f);
    float v = sq * (1.f / 256.f) - m * m;
    s_mean[tid] = m; s_rstd[tid] = rsqrtf(v + 1e-5f);
  }

  floatx4 acc[2][8];
  for (int rt = 0; rt < 2; rt++)
    for (int ct = 0; ct < 8; ct++) acc[rt][ct] = (floatx4){0.f, 0.f, 0.f, 0.f};

  for (int c = 0; c < 4; c++) {
    __syncthreads();
    for (int i = 0; i < 4; i++) {
      int g = tid + 256 * i;
      int row = g >> 3, c8 = g & 7;
      int col0 = c * 64 + c8 * 8;
      const float* p = x + (r0 + row) * 256 + col0;
      float4 d0 = ((const float4*)p)[0];
      float4 d1 = ((const float4*)p)[1];
      float f[8] = {d0.x, d0.y, d0.z, d0.w, d1.x, d1.y, d1.z, d1.w};
      float m = s_mean[row], rs = s_rstd[row];
      half8 hv;
      #pragma unroll
      for (int j = 0; j < 8; j++)
        hv[j] = (_Float16)((f[j] - m) * rs * s_lnw[col0 + j] + s_lnb[col0 + j]);
      *(half8*)&u.s.A[row][c8 * 8] = hv;
      *(half8*)&u.s.B[row][c8 * 8] = *(const half8*)(WT + (size_t)(y * 128 + row) * 256 + col0);
    }
    __syncthreads();
    #pragma unroll
    for (int ks = 0; ks < 2; ks++) {
      half8 af[2];
      af[0] = *(const half8*)&u.s.A[(2 * w) * 16 + l15][ks * 32 + quad * 8];
      af[1] = *(const half8*)&u.s.A[(2 * w + 1) * 16 + l15][ks * 32 + quad * 8];
      #pragma unroll
      for (int ct = 0; ct < 8; ct++) {
        half8 bf = *(const half8*)&u.s.B[ct * 16 + l15][ks * 32 + quad * 8];
        acc[0][ct] = MFMA_F16(af[0], bf, acc[0][ct]);
        acc[1][ct] = MFMA_F16(af[1], bf, acc[1][ct]);
      }
    }
  }

  const size_t bt = (size_t)(bx >> 3);
  const int n0loc = (bx & 7) * 128;
  if (y == 0) {
    for (int rt = 0; rt < 2; rt++)
      for (int ct = 0; ct < 8; ct++)
        #pragma unroll
        for (int r = 0; r < 4; r++) {
          size_t row = r0 + (2 * w + rt) * 16 + quad * 4 + r;
          kout[row * 128 + ct * 16 + l15] = (_Float16)acc[rt][ct][r];
        }
  } else {
    __syncthreads();
    for (int rt = 0; rt < 2; rt++)
      for (int ct = 0; ct < 8; ct++)
        #pragma unroll
        for (int r = 0; r < 4; r++)
          u.C[(2 * w + rt) * 16 + quad * 4 + r][ct * 16 + l15] = (_Float16)acc[rt][ct][r];
    __syncthreads();
    int s = tid >> 1, hf = tid & 1;
    for (int j = 0; j < 8; j++) {
      int nb = hf * 64 + j * 8;
      half8 tmp;
      #pragma unroll
      for (int e = 0; e < 8; e++) tmp[e] = u.C[nb + e][s];
      *(half8*)(vTout + (bt * 128 + s) * 1024 + n0loc + nb) = tmp;
    }
  }
}

// ---------------------------------------------------------------------------
// phase 2: slot-attention scan. grid 128 (= 16 batches x 8 n-groups), 1024 thr.
// Changes vs prior: gh GEMM overlapped onto waves 8-15 during w<8-only phases;
// weight B-fragments register-prefetched one phase early; gates+LN fused into
// a single wave-parallel phase (also writes out_slots from regs).
// ---------------------------------------------------------------------------
struct P2Args {
  const _Float16 *kbuf, *vT;
  const _Float16 *WqT, *Wih, *Whh, *W1T, *W2T;
  const _Float16 *pQT, *pKT, *pVT, *pOT, *pF1T, *pF2T;
  const float *noise, *mu, *lsig;
  const float *lnsw, *lnsb, *lnmw, *lnmb;
  const float *bih, *bhh, *mb1, *mb2;
  const float *pl1w, *pl1b, *pl2w, *pl2b, *fb1, *fb2, *plfw, *plfb;
  float *out_slots, *out_attn;
  float *upd_p;   // [2][16][8][8*128]
  float *col_p;   // [2][16][8][8]
  float *vs_p;    // [16][8][128]
  int   *ctr;     // [16]
};

struct SH {
  _Float16 k_lds[128][136];   // k slice [n_local][s]
  _Float16 v_lds[128][136];   // v slice [s][n_local]
  float slots[8][128];
  _Float16 a16[16][136];
  _Float16 h16[16][136];
  float gi[8][384];           // dedicated (not unioned): gh written by waves
  float gh[8][384];           // 8-15 concurrently with sa-union phases
  union {
    struct { _Float16 qT[16][136]; _Float16 attnT[16][136]; } sa;
    struct { _Float16 m16[16][264]; } mlp;
    struct { float qh[8][128]; float kh[8][128]; float vh[8][128]; float sc[4][8][8]; } mha;
    struct { _Float16 f16[16][520]; } ffn;
  } u;
  float colsum[8];
  float vsum[128];
  float bih[384], bhh[384], mb1[256], mb2[128], fb1[512], fb2[128];
  float lnsw[128], lnsb[128], lnmw[128], lnmb[128];
  float pl1w[128], pl1b[128], pl2w[128], pl2b[128], plfw[128], plfb[128];
};

__device__ __forceinline__ void group_barrier(int* ctr, int target) {
  __syncthreads();   // drains vmcnt: all agent-scope stores complete
  if (threadIdx.x == 0) {
    __hip_atomic_fetch_add(ctr, 1, __ATOMIC_ACQ_REL, __HIP_MEMORY_SCOPE_AGENT);
    while (__hip_atomic_load(ctr, __ATOMIC_ACQUIRE, __HIP_MEMORY_SCOPE_AGENT) < target)
      __builtin_amdgcn_s_sleep(1);
  }
  __syncthreads();
}

__device__ __forceinline__ void ln_to_a16(SH* sh, const float (*src)[128],
                                          const float* wv, const float* bv,
                                          int w, int lane) {
  if (w < 8) {
    float x0 = src[w][lane], x1 = src[w][lane + 64];
    float s = x0 + x1, sq = x0 * x0 + x1 * x1;
    #pragma unroll
    for (int m = 1; m < 64; m <<= 1) { s += __shfl_xor(s, m); sq += __shfl_xor(sq, m); }
    float mn = s * 0.0078125f;
    float vr = sq * 0.0078125f - mn * mn;
    float rs = rsqrtf(vr + 1e-5f);
    sh->a16[w][lane]      = (_Float16)((x0 - mn) * rs * wv[lane]      + bv[lane]);
    sh->a16[w][lane + 64] = (_Float16)((x1 - mn) * rs * wv[lane + 64] + bv[lane + 64]);
  } else {
    sh->a16[w][lane] = (_Float16)0.f;
    sh->a16[w][lane + 64] = (_Float16)0.f;
  }
}

__global__ __launch_bounds__(1024) void slot_attn_kernel(P2Args P) {
  __shared__ SH sh;
  const int tid = threadIdx.x;
  const int w = tid >> 6, lane = tid & 63, quad = lane >> 4, l15 = lane & 15;
  const int b = blockIdx.x & 15;       // batch
  const int g = blockIdx.x >> 4;       // n-group (0..7) -> same XCD for fixed b
  const int n0 = g * 128;
  int* ctrb = P.ctr + b;
  int bar_phase = 0;

  for (int i = tid; i < 384; i += 1024) { sh.bih[i] = P.bih[i]; sh.bhh[i] = P.bhh[i]; }
  for (int i = tid; i < 256; i += 1024) sh.mb1[i] = P.mb1[i];
  for (int i = tid; i < 512; i += 1024) sh.fb1[i] = P.fb1[i];
  if (tid < 128) {
    sh.mb2[tid]  = P.mb2[tid];  sh.fb2[tid]  = P.fb2[tid];
    sh.lnsw[tid] = P.lnsw[tid]; sh.lnsb[tid] = P.lnsb[tid];
    sh.lnmw[tid] = P.lnmw[tid]; sh.lnmb[tid] = P.lnmb[tid];
    sh.pl1w[tid] = P.pl1w[tid]; sh.pl1b[tid] = P.pl1b[tid];
    sh.pl2w[tid] = P.pl2w[tid]; sh.pl2b[tid] = P.pl2b[tid];
    sh.plfw[tid] = P.plfw[tid]; sh.plfb[tid] = P.plfb[tid];
  }
  {
    int kk = tid >> 7, s = tid & 127;
    sh.slots[kk][s] = P.mu[s] + expf(P.lsig[s]) * P.noise[(b * 8 + kk) * 128 + s];
  }
  __syncthreads();

  for (int t = 0; t < 12; t++) {
    const _Float16* kt = P.kbuf + ((size_t)(b * 12 + t)) * 1024 * 128 + (size_t)n0 * 128;
    const _Float16* vt = P.vT   + ((size_t)(b * 12 + t)) * 128 * 1024 + n0;
    // ---- stage k/v slice into LDS (32 KB each)
    {
      int r = tid >> 4, c8 = (tid & 15) * 8;
      #pragma unroll
      for (int p = 0; p < 2; p++) {
        int row = p * 64 + r;
        *(half8*)&sh.k_lds[row][c8] = *(const half8*)(kt + (size_t)row * 128 + c8);
        *(half8*)&sh.v_lds[row][c8] = *(const half8*)(vt + (size_t)row * 1024 + c8);
      }
    }
    if (tid < 128) sh.vsum[tid] = 0.f;
    __syncthreads();
    // ---- vsum partial over local n from v_lds
    {
      int s = tid >> 3, j = tid & 7;
      float a = 0.f;
      #pragma unroll
      for (int e = 0; e < 16; e++) a += (float)sh.v_lds[s][j * 16 + e];
      atomicAdd(&sh.vsum[s], a);
    }
    __syncthreads();
    if (tid < 128)
      __hip_atomic_store(&P.vs_p[(b * 8 + g) * 128 + tid], sh.vsum[tid],
                         __ATOMIC_RELAXED, __HIP_MEMORY_SCOPE_AGENT);

    half8 qkvf[4];   // predictor QKV prefetch (loaded at it==2 gates phase)

    for (int it = 0; it < 3; it++) {
      const int par = (t * 3 + it) & 1;
      float* updg = P.upd_p + ((size_t)(par * 16 + b) * 8 + g) * 1024;
      float* colg = P.col_p + ((size_t)(par * 16 + b) * 8 + g) * 8;
      half8 wqf[4], gif[4], w1f[4], w2f[8], whf[12];
      // ---- ph1: LN(slots) -> a16 rows 0..7; h16 = f16(slots); Wq prefetch
      if (w < 8) {
        {
          const _Float16* br = P.WqT + (size_t)(w * 16 + l15) * 128 + quad * 8;
          #pragma unroll
          for (int ks = 0; ks < 4; ks++) wqf[ks] = *(const half8*)(br + ks * 32);
        }
        float x0 = sh.slots[w][lane], x1 = sh.slots[w][lane + 64];
        sh.h16[w][lane] = (_Float16)x0; sh.h16[w][lane + 64] = (_Float16)x1;
        float s = x0 + x1, sq = x0 * x0 + x1 * x1;
        #pragma unroll
        for (int m = 1; m < 64; m <<= 1) { s += __shfl_xor(s, m); sq += __shfl_xor(sq, m); }
        float mn = s * 0.0078125f;
        float vr = sq * 0.0078125f - mn * mn;
        float rs = rsqrtf(vr + 1e-5f);
        sh.a16[w][lane]      = (_Float16)((x0 - mn) * rs * sh.lnsw[lane]      + sh.lnsb[lane]);
        sh.a16[w][lane + 64] = (_Float16)((x1 - mn) * rs * sh.lnsw[lane + 64] + sh.lnsb[lane + 64]);
      } else {
        sh.h16[w][lane] = (_Float16)0.f; sh.h16[w][lane + 64] = (_Float16)0.f;
        sh.a16[w][lane] = (_Float16)0.f; sh.a16[w][lane + 64] = (_Float16)0.f;
      }
      if (tid < 8) sh.colsum[tid] = 0.f;
      __syncthreads();
      // ---- ph2: w<8: q = y @ Wq -> qT ; w>=8: gh tiles 0,1 (of 3)
      if (w < 8) {
        floatx4 acc = (floatx4){0.f, 0.f, 0.f, 0.f};
        const _Float16* ar = &sh.a16[l15][quad * 8];
        #pragma unroll
        for (int ks = 0; ks < 4; ks++)
          acc = MFMA_F16(*(const half8*)(ar + ks * 32), wqf[ks], acc);
        #pragma unroll
        for (int r = 0; r < 4; r++)
          sh.u.sa.qT[quad * 4 + r][w * 16 + l15] = (_Float16)acc[r];
      } else {
        const int idx8 = w - 8;
        #pragma unroll
        for (int tt = 0; tt < 3; tt++) {
          int ct = idx8 + tt * 8;
          const _Float16* Bg = P.Whh + (size_t)(ct * 16 + l15) * 128 + quad * 8;
          #pragma unroll
          for (int ks = 0; ks < 4; ks++) whf[tt * 4 + ks] = *(const half8*)(Bg + ks * 32);
        }
        #pragma unroll
        for (int tt = 0; tt < 2; tt++) {
          floatx4 acc = (floatx4){0.f, 0.f, 0.f, 0.f};
          const _Float16* ar = &sh.h16[l15][quad * 8];
          #pragma unroll
          for (int ks = 0; ks < 4; ks++)
            acc = MFMA_F16(*(const half8*)(ar + ks * 32), whf[tt * 4 + ks], acc);
          int col = (idx8 + tt * 8) * 16 + l15;
          #pragma unroll
          for (int r = 0; r < 4; r++) {
            int slot = quad * 4 + r;
            if (slot < 8) sh.gh[slot][col] = acc[r] + sh.bhh[col];
          }
        }
      }
      __syncthreads();
      // ---- ph3: gi prefetch (all waves); w<8: logits+softmax; w>=8: gh tile 2
      {
        const _Float16* Bg = P.Wih + (size_t)(w * 16 + l15) * 128 + quad * 8;
        #pragma unroll
        for (int ks = 0; ks < 4; ks++) gif[ks] = *(const half8*)(Bg + ks * 32);
      }
      if (w < 8) {
        int nloc0 = w * 16;
        floatx4 acc = (floatx4){0.f, 0.f, 0.f, 0.f};
        const _Float16* ar = &sh.k_lds[nloc0 + l15][quad * 8];
        const _Float16* br = &sh.u.sa.qT[l15][quad * 8];
        #pragma unroll
        for (int ks = 0; ks < 4; ks++)
          acc = MFMA_F16(*(const half8*)(ar + ks * 32), *(const half8*)(br + ks * 32), acc);
        float cs = 0.f;
        #pragma unroll
        for (int r = 0; r < 4; r++) {
          float v = (l15 < 8) ? acc[r] : -3.0e38f;
          float mx = v;
          mx = fmaxf(mx, __shfl_xor(mx, 1, 16));
          mx = fmaxf(mx, __shfl_xor(mx, 2, 16));
          mx = fmaxf(mx, __shfl_xor(mx, 4, 16));
          mx = fmaxf(mx, __shfl_xor(mx, 8, 16));
          float pv = (l15 < 8) ? expf(v - mx) : 0.f;
          float ss = pv;
          ss += __shfl_xor(ss, 1, 16); ss += __shfl_xor(ss, 2, 16);
          ss += __shfl_xor(ss, 4, 16); ss += __shfl_xor(ss, 8, 16);
          float pn = pv / ss;
          cs += pn;
          int nloc = nloc0 + quad * 4 + r;
          sh.u.sa.attnT[l15][nloc] = (_Float16)pn;
          if (it == 2 && l15 < 8)
            P.out_attn[((size_t)(b * 12 + t) * 1024 + n0 + nloc) * 8 + l15] = pn;
        }
        cs += __shfl_xor(cs, 16); cs += __shfl_xor(cs, 32);
        if (lane < 8) atomicAdd(&sh.colsum[lane], cs);
      } else {
        const int idx8 = w - 8;
        floatx4 acc = (floatx4){0.f, 0.f, 0.f, 0.f};
        const _Float16* ar = &sh.h16[l15][quad * 8];
        #pragma unroll
        for (int ks = 0; ks < 4; ks++)
          acc = MFMA_F16(*(const half8*)(ar + ks * 32), whf[8 + ks], acc);
        int col = (idx8 + 16) * 16 + l15;
        #pragma unroll
        for (int r = 0; r < 4; r++) {
          int slot = quad * 4 + r;
          if (slot < 8) sh.gh[slot][col] = acc[r] + sh.bhh[col];
        }
      }
      __syncthreads();
      // ---- ph4: W1T prefetch; w<8: partial updates = P^T @ v -> global
      if (it < 2) {
        const _Float16* Bg = P.W1T + (size_t)(w * 16 + l15) * 128 + quad * 8;
        #pragma unroll
        for (int ks = 0; ks < 4; ks++) w1f[ks] = *(const half8*)(Bg + ks * 32);
      }
      if (w < 8) {
        floatx4 acc = (floatx4){0.f, 0.f, 0.f, 0.f};
        const _Float16* ar = &sh.u.sa.attnT[l15][quad * 8];
        const _Float16* br = &sh.v_lds[w * 16 + l15][quad * 8];
        #pragma unroll
        for (int ks = 0; ks < 4; ks++)
          acc = MFMA_F16(*(const half8*)(ar + ks * 32), *(const half8*)(br + ks * 32), acc);
        int scol = w * 16 + l15;
        #pragma unroll
        for (int r = 0; r < 4; r++) {
          int slot = quad * 4 + r;
          if (slot < 8)
            __hip_atomic_store(&updg[slot * 128 + scol], acc[r],
                               __ATOMIC_RELAXED, __HIP_MEMORY_SCOPE_AGENT);
        }
      }
      if (tid < 8)
        __hip_atomic_store(&colg[tid], sh.colsum[tid],
                           __ATOMIC_RELAXED, __HIP_MEMORY_SCOPE_AGENT);
      // ---- 8-block barrier
      bar_phase++;
      group_barrier(ctrb, 8 * bar_phase);
      // ---- reduce partials; fold eps renorm -> a16
      {
        int slot = tid >> 7, scol = tid & 127;
        const float* up = P.upd_p + (size_t)(par * 16 + b) * 8 * 1024 + slot * 128 + scol;
        float sum = 0.f;
        #pragma unroll
        for (int gg = 0; gg < 8; gg++)
          sum += __hip_atomic_load((float*)(up + gg * 1024),
                                   __ATOMIC_RELAXED, __HIP_MEMORY_SCOPE_AGENT);
        float csum = 0.f;
        if (tid < 8) {
          const float* cp = P.col_p + (size_t)(par * 16 + b) * 8 * 8 + tid;
          #pragma unroll
          for (int gg = 0; gg < 8; gg++)
            csum += __hip_atomic_load((float*)(cp + gg * 8),
                                      __ATOMIC_RELAXED, __HIP_MEMORY_SCOPE_AGENT);
        }
        float vtot = 0.f;
        if (it == 0 && tid < 128) {
          const float* vp = P.vs_p + b * 8 * 128 + tid;
          #pragma unroll
          for (int gg = 0; gg < 8; gg++)
            vtot += __hip_atomic_load((float*)(vp + gg * 128),
                                      __ATOMIC_RELAXED, __HIP_MEMORY_SCOPE_AGENT);
        }
        __syncthreads();
        if (tid < 8) sh.colsum[tid] = csum;
        if (it == 0 && tid < 128) sh.vsum[tid] = vtot;
        __syncthreads();
        float upd = (sum + 1e-8f * sh.vsum[scol]) / (sh.colsum[slot] + 1024.f * 1e-8f);
        sh.a16[slot][scol] = (_Float16)upd;
      }
      __syncthreads();
      // ---- GRU gi: all waves tile ct=w (prefetched); w<8 also ct=16+w
      {
        const _Float16* ar = &sh.a16[l15][quad * 8];
        floatx4 acc = (floatx4){0.f, 0.f, 0.f, 0.f};
        #pragma unroll
        for (int ks = 0; ks < 4; ks++)
          acc = MFMA_F16(*(const half8*)(ar + ks * 32), gif[ks], acc);
        int col = w * 16 + l15;
        #pragma unroll
        for (int r = 0; r < 4; r++) {
          int slot = quad * 4 + r;
          if (slot < 8) sh.gi[slot][col] = acc[r] + sh.bih[col];
        }
        if (w < 8) {
          int col2 = (16 + w) * 16 + l15;
          const _Float16* Bg = P.Wih + (size_t)((16 + w) * 16 + l15) * 128 + quad * 8;
          floatx4 acc2 = (floatx4){0.f, 0.f, 0.f, 0.f};
          #pragma unroll
          for (int ks = 0; ks < 4; ks++)
            acc2 = MFMA_F16(*(const half8*)(ar + ks * 32), *(const half8*)(Bg + ks * 32), acc2);
          #pragma unroll
          for (int r = 0; r < 4; r++) {
            int slot = quad * 4 + r;
            if (slot < 8) sh.gi[slot][col2] = acc2[r] + sh.bih[col2];
          }
        }
      }
      __syncthreads();
      // ---- gates + LN fused (waves 0-7); prefetch W2T (it<2) / QKV (it==2)
      if (it < 2) {
        if (w < 8) {
          const _Float16* Bg = P.W2T + (size_t)(w * 16 + l15) * 256 + quad * 8;
          #pragma unroll
          for (int ks = 0; ks < 8; ks++) w2f[ks] = *(const half8*)(Bg + ks * 32);
        }
      } else {
        const _Float16* Bg = ((w >> 3) == 0 ? P.pQT : P.pKT) + (size_t)((w & 7) * 16 + l15) * 128 + quad * 8;
        #pragma unroll
        for (int ks = 0; ks < 4; ks++) qkvf[ks] = *(const half8*)(Bg + ks * 32);
      }
      if (w < 8) {
        float h0 = sh.slots[w][lane], h1 = sh.slots[w][lane + 64];
        float r0 = 1.f / (1.f + expf(-(sh.gi[w][lane]       + sh.gh[w][lane])));
        float z0 = 1.f / (1.f + expf(-(sh.gi[w][128 + lane] + sh.gh[w][128 + lane])));
        float n0v = tanhf(sh.gi[w][256 + lane] + r0 * sh.gh[w][256 + lane]);
        float x0 = (1.f - z0) * n0v + z0 * h0;
        int l64 = lane + 64;
        float r1 = 1.f / (1.f + expf(-(sh.gi[w][l64]       + sh.gh[w][l64])));
        float z1 = 1.f / (1.f + expf(-(sh.gi[w][128 + l64] + sh.gh[w][128 + l64])));
        float n1v = tanhf(sh.gi[w][256 + l64] + r1 * sh.gh[w][256 + l64]);
        float x1 = (1.f - z1) * n1v + z1 * h1;
        sh.slots[w][lane] = x0; sh.slots[w][lane + 64] = x1;
        if (it == 2 && g == 0) {
          P.out_slots[((size_t)(b * 12 + t) * 8 + w) * 128 + lane]      = x0;
          P.out_slots[((size_t)(b * 12 + t) * 8 + w) * 128 + lane + 64] = x1;
        }
        // fused LN -> a16 (lnm for MLP iters, pl1 for predictor entry)
        const float* wv = (it < 2) ? sh.lnmw : sh.pl1w;
        const float* bv = (it < 2) ? sh.lnmb : sh.pl1b;
        float s = x0 + x1, sq = x0 * x0 + x1 * x1;
        #pragma unroll
        for (int m = 1; m < 64; m <<= 1) { s += __shfl_xor(s, m); sq += __shfl_xor(sq, m); }
        float mn = s * 0.0078125f;
        float vr = sq * 0.0078125f - mn * mn;
        float rs = rsqrtf(vr + 1e-5f);
        sh.a16[w][lane]      = (_Float16)((x0 - mn) * rs * wv[lane]      + bv[lane]);
        sh.a16[w][lane + 64] = (_Float16)((x1 - mn) * rs * wv[lane + 64] + bv[lane + 64]);
      }
      __syncthreads();
      // ---- residual MLP (iters 0,1)
      if (it < 2) {
        {
          floatx4 acc = (floatx4){0.f, 0.f, 0.f, 0.f};
          const _Float16* ar = &sh.a16[l15][quad * 8];
          #pragma unroll
          for (int ks = 0; ks < 4; ks++)
            acc = MFMA_F16(*(const half8*)(ar + ks * 32), w1f[ks], acc);
          int col = w * 16 + l15;
          #pragma unroll
          for (int r = 0; r < 4; r++) {
            int slot = quad * 4 + r;
            if (slot < 8) sh.u.mlp.m16[slot][col] = (_Float16)fmaxf(acc[r] + sh.mb1[col], 0.f);
            else          sh.u.mlp.m16[slot][col] = (_Float16)0.f;
          }
        }
        __syncthreads();
        if (w < 8) {
          floatx4 acc = (floatx4){0.f, 0.f, 0.f, 0.f};
          const _Float16* ar = &sh.u.mlp.m16[l15][quad * 8];
          #pragma unroll
          for (int ks = 0; ks < 8; ks++)
            acc = MFMA_F16(*(const half8*)(ar + ks * 32), w2f[ks], acc);
          int col = w * 16 + l15;
          #pragma unroll
          for (int r = 0; r < 4; r++) {
            int slot = quad * 4 + r;
            if (slot < 8) sh.slots[slot][col] += acc[r] + sh.mb2[col];
          }
        }
        __syncthreads();
      }
    } // it

    // ---- predictor (redundant, identical in all 8 blocks); a16 = LN_pl1(slots)
    // QKV: wave w does tile j=w (prefetched q/k); w<8 also j=16+w (pVT, in-phase)
    {
      const _Float16* ar = &sh.a16[l15][quad * 8];
      floatx4 acc = (floatx4){0.f, 0.f, 0.f, 0.f};
      #pragma unroll
      for (int ks = 0; ks < 4; ks++)
        acc = MFMA_F16(*(const half8*)(ar + ks * 32), qkvf[ks], acc);
      int gg = w >> 3, ct = w & 7, col = ct * 16 + l15;
      float scale = (gg == 0) ? 0.17677669529663687f : 1.f;
      float* dst = (gg == 0) ? &sh.u.mha.qh[0][0] : &sh.u.mha.kh[0][0];
      #pragma unroll
      for (int r = 0; r < 4; r++) {
        int slot = quad * 4 + r;
        if (slot < 8) dst[slot * 128 + col] = acc[r] * scale;
      }
      if (w < 8) {
        const _Float16* Bg = P.pVT + (size_t)(w * 16 + l15) * 128 + quad * 8;
        floatx4 a2 = (floatx4){0.f, 0.f, 0.f, 0.f};
        #pragma unroll
        for (int ks = 0; ks < 4; ks++)
          a2 = MFMA_F16(*(const half8*)(ar + ks * 32), *(const half8*)(Bg + ks * 32), a2);
        int colv = w * 16 + l15;
        #pragma unroll
        for (int r = 0; r < 4; r++) {
          int slot = quad * 4 + r;
          if (slot < 8) sh.u.mha.vh[slot][colv] = a2[r];
        }
      }
    }
    __syncthreads();
    if (tid < 256) {
      int h = tid >> 6, a = (tid >> 3) & 7, b2 = tid & 7;
      const float* qr = &sh.u.mha.qh[a][h * 32];
      const float* kr = &sh.u.mha.kh[b2][h * 32];
      float s = 0.f;
      #pragma unroll
      for (int d = 0; d < 32; d++) s += qr[d] * kr[d];
      sh.u.mha.sc[h][a][b2] = s;
    }
    __syncthreads();
    if (tid < 32) {
      int h = tid >> 3, a = tid & 7;
      float* p = sh.u.mha.sc[h][a];
      float mx = p[0];
      #pragma unroll
      for (int j = 1; j < 8; j++) mx = fmaxf(mx, p[j]);
      float e[8]; float ssum = 0.f;
      #pragma unroll
      for (int j = 0; j < 8; j++) { e[j] = expf(p[j] - mx); ssum += e[j]; }
      float inv = 1.f / ssum;
      #pragma unroll
      for (int j = 0; j < 8; j++) p[j] = e[j] * inv;
    }
    __syncthreads();
    {
      int a = tid >> 7, col = tid & 127, h = col >> 5;
      float acc = 0.f;
      #pragma unroll
      for (int b2 = 0; b2 < 8; b2++) acc += sh.u.mha.sc[h][a][b2] * sh.u.mha.vh[b2][col];
      sh.a16[a][col] = (_Float16)acc;
    }
    __syncthreads();
    if (w < 8) {       // s += o @ Wo
      floatx4 acc = (floatx4){0.f, 0.f, 0.f, 0.f};
      const _Float16* ar = &sh.a16[l15][quad * 8];
      const _Float16* br = P.pOT + (size_t)(w * 16 + l15) * 128 + quad * 8;
      #pragma unroll
      for (int ks = 0; ks < 4; ks++)
        acc = MFMA_F16(*(const half8*)(ar + ks * 32), *(const half8*)(br + ks * 32), acc);
      int col = w * 16 + l15;
      #pragma unroll
      for (int r = 0; r < 4; r++) {
        int slot = quad * 4 + r;
        if (slot < 8) sh.slots[slot][col] += acc[r];
      }
    }
    __syncthreads();
    ln_to_a16(&sh, sh.slots, sh.pl2w, sh.pl2b, w, lane);
    __syncthreads();
    for (int ct = w; ct < 32; ct += 16) {   // FFN1 + relu
      floatx4 acc = (floatx4){0.f, 0.f, 0.f, 0.f};
      const _Float16* ar = &sh.a16[l15][quad * 8];
      const _Float16* br = P.pF1T + (size_t)(ct * 16 + l15) * 128 + quad * 8;
      #pragma unroll
      for (int ks = 0; ks < 4; ks++)
        acc = MFMA_F16(*(const half8*)(ar + ks * 32), *(const half8*)(br + ks * 32), acc);
      int col = ct * 16 + l15;
      #pragma unroll
      for (int r = 0; r < 4; r++) {
        int slot = quad * 4 + r;
        if (slot < 8) sh.u.ffn.f16[slot][col] = (_Float16)fmaxf(acc[r] + sh.fb1[col], 0.f);
        else          sh.u.ffn.f16[slot][col] = (_Float16)0.f;
      }
    }
    __syncthreads();
    if (w < 8) {       // FFN2 + residual
      floatx4 acc = (floatx4){0.f, 0.f, 0.f, 0.f};
      const _Float16* ar = &sh.u.ffn.f16[l15][quad * 8];
      const _Float16* br = P.pF2T + (size_t)(w * 16 + l15) * 512 + quad * 8;
      #pragma unroll 4
      for (int ks = 0; ks < 16; ks++)
        acc = MFMA_F16(*(const half8*)(ar + ks * 32), *(const half8*)(br + ks * 32), acc);
      int col = w * 16 + l15;
      #pragma unroll
      for (int r = 0; r < 4; r++) {
        int slot = quad * 4 + r;
        if (slot < 8) sh.slots[slot][col] += acc[r] + sh.fb2[col];
      }
    }
    __syncthreads();
    if (w < 8) {       // final LN -> carry
      float x0 = sh.slots[w][lane], x1 = sh.slots[w][lane + 64];
      float s = x0 + x1, sq = x0 * x0 + x1 * x1;
      #pragma unroll
      for (int m = 1; m < 64; m <<= 1) { s += __shfl_xor(s, m); sq += __shfl_xor(sq, m); }
      float mn = s * 0.0078125f;
      float vr = sq * 0.0078125f - mn * mn;
      float rs = rsqrtf(vr + 1e-5f);
      sh.slots[w][lane]      = (x0 - mn) * rs * sh.plfw[lane]      + sh.plfb[lane];
      sh.slots[w][lane + 64] = (x1 - mn) * rs * sh.plfw[lane + 64] + sh.plfb[lane + 64];
    }
    __syncthreads();
  } // t
}

// ---------------------------------------------------------------------------
extern "C" void kernel_launch(void* const* d_in, const int* in_sizes, int n_in,
                              void* d_out, int out_size, void* d_ws, size_t ws_size,
                              hipStream_t stream) {
  const float* inp   = (const float*)d_in[0];
  const float* noise = (const float*)d_in[1];
  const float* mu    = (const float*)d_in[2];
  const float* lsig  = (const float*)d_in[3];
  const float* lniw  = (const float*)d_in[4];
  const float* lnib  = (const float*)d_in[5];
  const float* lnsw  = (const float*)d_in[6];
  const float* lnsb  = (const float*)d_in[7];
  const float* lnmw  = (const float*)d_in[8];
  const float* lnmb  = (const float*)d_in[9];
  const float* Wq    = (const float*)d_in[10];
  const float* Wk    = (const float*)d_in[11];
  const float* Wv    = (const float*)d_in[12];
  const float* gWih  = (const float*)d_in[13];
  const float* gWhh  = (const float*)d_in[14];
  const float* gbih  = (const float*)d_in[15];
  const float* gbhh  = (const float*)d_in[16];
  const float* mW1   = (const float*)d_in[17];
  const float* mb1   = (const float*)d_in[18];
  const float* mW2   = (const float*)d_in[19];
  const float* mb2   = (const float*)d_in[20];
  const float* pl1w  = (const float*)d_in[21];
  const float* pl1b  = (const float*)d_in[22];
  const float* pWq   = (const float*)d_in[23];
  const float* pWk   = (const float*)d_in[24];
  const float* pWv   = (const float*)d_in[25];
  const float* pWo   = (const float*)d_in[26];
  const float* pl2w  = (const float*)d_in[27];
  const float* pl2b  = (const float*)d_in[28];
  const float* pf1   = (const float*)d_in[29];
  const float* pfb1  = (const float*)d_in[30];
  const float* pf2   = (const float*)d_in[31];
  const float* pfb2  = (const float*)d_in[32];
  const float* plfw  = (const float*)d_in[33];
  const float* plfb  = (const float*)d_in[34];

  // workspace layout (f16 elements); ~101.5 MB + ~0.6 MB partials
  _Float16* p   = (_Float16*)d_ws;
  _Float16* kbuf = p;  p += 25165824;
  _Float16* vT   = p;  p += 25165824;
  _Float16* WT   = p;  p += 65536;
  _Float16* WqT  = p;  p += 16384;
  _Float16* Wih  = p;  p += 49152;
  _Float16* Whh  = p;  p += 49152;
  _Float16* W1T  = p;  p += 32768;
  _Float16* W2T  = p;  p += 32768;
  _Float16* pQT  = p;  p += 16384;
  _Float16* pKT  = p;  p += 16384;
  _Float16* pVT  = p;  p += 16384;
  _Float16* pOT  = p;  p += 16384;
  _Float16* pF1T = p;  p += 65536;
  _Float16* pF2T = p;  p += 65536;
  float* fb   = (float*)p;
  float* upd_p = fb;  fb += 2 * 16 * 8 * 1024;   // 131072
  float* col_p = fb;  fb += 2 * 16 * 8 * 8;      // 2048
  float* vs_p  = fb;  fb += 16 * 8 * 128;        // 16384
  int*   ctr   = (int*)fb;                       // 16

  const float kscale = 0.08838834764831845f;  // S^-0.5, S=128
  init_ctr_kernel<<<1, 64, 0, stream>>>(ctr);

  PrepJobs J;
  const float* srcs[13] = {Wk, Wv, Wq, gWih, gWhh, mW1, mW2, pWq, pWk, pWv, pWo, pf1, pf2};
  _Float16* dsts[13]    = {WT, WT + 32768, WqT, Wih, Whh, W1T, W2T, pQT, pKT, pVT, pOT, pF1T, pF2T};
  int Ins[13]    = {256, 256, 128, 49152, 49152, 128, 256, 128, 128, 128, 128, 128, 512};
  int Outs[13]   = {128, 128, 128, 1, 1, 256, 128, 128, 128, 128, 128, 512, 128};
  int elemss[13] = {32768, 32768, 16384, 49152, 49152, 32768, 32768, 16384, 16384, 16384, 16384, 65536, 65536};
  int doTs[13]   = {1, 1, 1, 0, 0, 1, 1, 1, 1, 1, 1, 1, 1};
  float scales[13] = {kscale, 1.f, 1.f, 1.f, 1.f, 1.f, 1.f, 1.f, 1.f, 1.f, 1.f, 1.f, 1.f};
  for (int j = 0; j < 13; j++) {
    J.src[j] = srcs[j]; J.dst[j] = dsts[j]; J.In[j] = Ins[j]; J.Out[j] = Outs[j];
    J.elems[j] = elemss[j]; J.doT[j] = doTs[j]; J.scale[j] = scales[j];
  }
  dim3 gp(256, 13, 1);
  prep_all_kernel<<<gp, 256, 0, stream>>>(J);

  dim3 g1(1536, 2, 1);
  gemm_kv_kernel<<<g1, 256, 0, stream>>>(inp, lniw, lnib, WT, kbuf, vT);

  P2Args a;
  a.kbuf = kbuf; a.vT = vT;
  a.WqT = WqT; a.Wih = Wih; a.Whh = Whh; a.W1T = W1T; a.W2T = W2T;
  a.pQT = pQT; a.pKT = pKT; a.pVT = pVT; a.pOT = pOT; a.pF1T = pF1T; a.pF2T = pF2T;
  a.noise = noise; a.mu = mu; a.lsig = lsig;
  a.lnsw = lnsw; a.lnsb = lnsb; a.lnmw = lnmw; a.lnmb = lnmb;
  a.bih = gbih; a.bhh = gbhh; a.mb1 = mb1; a.mb2 = mb2;
  a.pl1w = pl1w; a.pl1b = pl1b; a.pl2w = pl2w; a.pl2b = pl2b;
  a.fb1 = pfb1; a.fb2 = pfb2; a.plfw = plfw; a.plfb = plfb;
  a.out_slots = (float*)d_out;
  a.out_attn  = (float*)d_out + 196608;
  a.upd_p = upd_p; a.col_p = col_p; a.vs_p = vs_p; a.ctr = ctr;

  slot_attn_kernel<<<128, 1024, 0, stream>>>(a);
}

// Round 4
// 1355.311 us; speedup vs baseline: 1.3044x; 1.3044x over previous
//
#include <hip/hip_runtime.h>
#include <hip/hip_bf16.h>

typedef _Float16 half8 __attribute__((ext_vector_type(8)));
typedef float floatx4 __attribute__((ext_vector_type(4)));

#define MFMA_F16(a, b, c) __builtin_amdgcn_mfma_f32_16x16x32_f16((a), (b), (c), 0, 0, 0)

// ---------------------------------------------------------------------------
// fused prep: 13 f32->f16 (optional transpose, scale) jobs in one launch.
// ---------------------------------------------------------------------------
struct PrepJobs {
  const float* src[13];
  _Float16* dst[13];
  int In[13], Out[13], elems[13], doT[13];
  float scale[13];
};

__global__ void prep_all_kernel(PrepJobs J) {
  int j = blockIdx.y;
  int idx = blockIdx.x * 256 + threadIdx.x;
  if (idx >= J.elems[j]) return;
  float v;
  if (J.doT[j]) { int o = idx / J.In[j], i = idx - o * J.In[j]; v = J.src[j][i * J.Out[j] + o]; }
  else          { v = J.src[j][idx]; }
  J.dst[j][idx] = (_Float16)(v * J.scale[j]);
}

__global__ void init_ctr_kernel(int* __restrict__ ctr) {
  if (threadIdx.x < 16) ctr[threadIdx.x] = 0;
}

// ---------------------------------------------------------------------------
// phase 1: fused LN + dual GEMM.  grid (1536, 2), 256 threads. (unchanged)
// ---------------------------------------------------------------------------
__global__ __launch_bounds__(256) void gemm_kv_kernel(
    const float* __restrict__ x, const float* __restrict__ lnw_g,
    const float* __restrict__ lnb_g, const _Float16* __restrict__ WT,
    _Float16* __restrict__ kout, _Float16* __restrict__ vTout) {
  __shared__ union {
    struct { _Float16 A[128][72]; _Float16 B[128][72]; } s;
    _Float16 C[128][136];
  } u;
  __shared__ float s_mean[128], s_rstd[128], s_red[256][2], s_lnw[256], s_lnb[256];

  const int tid = threadIdx.x;
  const int bx = blockIdx.x, y = blockIdx.y;
  const size_t r0 = (size_t)bx * 128;
  const int w = tid >> 6, lane = tid & 63, quad = lane >> 4, l15 = lane & 15;

  s_lnw[tid] = lnw_g[tid];
  s_lnb[tid] = lnb_g[tid];
  {
    int row = tid >> 1, half = tid & 1;
    const float* p = x + (r0 + row) * 256 + half * 128;
    float s = 0.f, sq = 0.f;
    for (int i = 0; i < 32; i++) {
      float4 d = ((const float4*)p)[i];
      s += d.x + d.y + d.z + d.w;
      sq += d.x * d.x + d.y * d.y + d.z * d.z + d.w * d.w;
    }
    s_red[tid][0] = s; s_red[tid][1] = sq;
  }
  __syncthreads();
  if (tid < 128) {
    float s  = s_red[2 * tid][0] + s_red[2 * tid + 1][0];
    float sq = s_red[2 * tid][1] + s_red[2 * tid + 1][1];
    float m = s * (1.f / 256.f);
    float v = sq * (1.f / 256.f) - m * m;
    s_mean[tid] = m; s_rstd[tid] = rsqrtf(v + 1e-5f);
  }

  floatx4 acc[2][8];
  for (int rt = 0; rt < 2; rt++)
    for (int ct = 0; ct < 8; ct++) acc[rt][ct] = (floatx4){0.f, 0.f, 0.f, 0.f};

  for (int c = 0; c < 4; c++) {
    __syncthreads();
    for (int i = 0; i < 4; i++) {
      int g = tid + 256 * i;
      int row = g >> 3, c8 = g & 7;
      int col0 = c * 64 + c8 * 8;
      const float* p = x + (r0 + row) * 256 + col0;
      float4 d0 = ((const float4*)p)[0];
      float4 d1 = ((const float4*)p)[1];
      float f[8] = {d0.x, d0.y, d0.z, d0.w, d1.x, d1.y, d1.z, d1.w};
      float m = s_mean[row], rs = s_rstd[row];
      half8 hv;
      #pragma unroll
      for (int j = 0; j < 8; j++)
        hv[j] = (_Float16)((f[j] - m) * rs * s_lnw[col0 + j] + s_lnb[col0 + j]);
      *(half8*)&u.s.A[row][c8 * 8] = hv;
      *(half8*)&u.s.B[row][c8 * 8] = *(const half8*)(WT + (size_t)(y * 128 + row) * 256 + col0);
    }
    __syncthreads();
    #pragma unroll
    for (int ks = 0; ks < 2; ks++) {
      half8 af[2];
      af[0] = *(const half8*)&u.s.A[(2 * w) * 16 + l15][ks * 32 + quad * 8];
      af[1] = *(const half8*)&u.s.A[(2 * w + 1) * 16 + l15][ks * 32 + quad * 8];
      #pragma unroll
      for (int ct = 0; ct < 8; ct++) {
        half8 bf = *(const half8*)&u.s.B[ct * 16 + l15][ks * 32 + quad * 8];
        acc[0][ct] = MFMA_F16(af[0], bf, acc[0][ct]);
        acc[1][ct] = MFMA_F16(af[1], bf, acc[1][ct]);
      }
    }
  }

  const size_t bt = (size_t)(bx >> 3);
  const int n0loc = (bx & 7) * 128;
  if (y == 0) {
    for (int rt = 0; rt < 2; rt++)
      for (int ct = 0; ct < 8; ct++)
        #pragma unroll
        for (int r = 0; r < 4; r++) {
          size_t row = r0 + (2 * w + rt) * 16 + quad * 4 + r;
          kout[row * 128 + ct * 16 + l15] = (_Float16)acc[rt][ct][r];
        }
  } else {
    __syncthreads();
    for (int rt = 0; rt < 2; rt++)
      for (int ct = 0; ct < 8; ct++)
        #pragma unroll
        for (int r = 0; r < 4; r++)
          u.C[(2 * w + rt) * 16 + quad * 4 + r][ct * 16 + l15] = (_Float16)acc[rt][ct][r];
    __syncthreads();
    int s = tid >> 1, hf = tid & 1;
    for (int j = 0; j < 8; j++) {
      int nb = hf * 64 + j * 8;
      half8 tmp;
      #pragma unroll
      for (int e = 0; e < 8; e++) tmp[e] = u.C[nb + e][s];
      *(half8*)(vTout + (bt * 128 + s) * 1024 + n0loc + nb) = tmp;
    }
  }
}

// ---------------------------------------------------------------------------
// phase 2: slot-attention scan. grid 128 (= 16 batches x 8 n-groups), 1024 thr.
// Round-4: all weight reads are DIRECT from L2 inside the MFMA loops (round-3
// register prefetch spilled to scratch at VGPR=64 -> 815MB HBM traffic).
// Kept from round-3: gh GEMM overlapped onto waves 8-15; fused gates+LN phase.
// __launch_bounds__(1024, 4): LDS caps at 1 block/CU (16 waves = 4 waves/EU),
// so allow the full 128-VGPR budget instead of the 64 default.
// ---------------------------------------------------------------------------
struct P2Args {
  const _Float16 *kbuf, *vT;
  const _Float16 *WqT, *Wih, *Whh, *W1T, *W2T;
  const _Float16 *pQT, *pKT, *pVT, *pOT, *pF1T, *pF2T;
  const float *noise, *mu, *lsig;
  const float *lnsw, *lnsb, *lnmw, *lnmb;
  const float *bih, *bhh, *mb1, *mb2;
  const float *pl1w, *pl1b, *pl2w, *pl2b, *fb1, *fb2, *plfw, *plfb;
  float *out_slots, *out_attn;
  float *upd_p;   // [2][16][8][8*128]
  float *col_p;   // [2][16][8][8]
  float *vs_p;    // [16][8][128]
  int   *ctr;     // [16]
};

struct SH {
  _Float16 k_lds[128][136];   // k slice [n_local][s]
  _Float16 v_lds[128][136];   // v slice [s][n_local]
  float slots[8][128];
  _Float16 a16[16][136];
  _Float16 h16[16][136];
  float gi[8][384];           // dedicated (not unioned): gh written by waves
  float gh[8][384];           // 8-15 concurrently with sa-union phases
  union {
    struct { _Float16 qT[16][136]; _Float16 attnT[16][136]; } sa;
    struct { _Float16 m16[16][264]; } mlp;
    struct { float qh[8][128]; float kh[8][128]; float vh[8][128]; float sc[4][8][8]; } mha;
    struct { _Float16 f16[16][520]; } ffn;
  } u;
  float colsum[8];
  float vsum[128];
  float bih[384], bhh[384], mb1[256], mb2[128], fb1[512], fb2[128];
  float lnsw[128], lnsb[128], lnmw[128], lnmb[128];
  float pl1w[128], pl1b[128], pl2w[128], pl2b[128], plfw[128], plfb[128];
};

__device__ __forceinline__ void group_barrier(int* ctr, int target) {
  __syncthreads();   // drains vmcnt: all agent-scope stores complete
  if (threadIdx.x == 0) {
    __hip_atomic_fetch_add(ctr, 1, __ATOMIC_ACQ_REL, __HIP_MEMORY_SCOPE_AGENT);
    while (__hip_atomic_load(ctr, __ATOMIC_ACQUIRE, __HIP_MEMORY_SCOPE_AGENT) < target)
      __builtin_amdgcn_s_sleep(1);
  }
  __syncthreads();
}

__device__ __forceinline__ void ln_to_a16(SH* sh, const float (*src)[128],
                                          const float* wv, const float* bv,
                                          int w, int lane) {
  if (w < 8) {
    float x0 = src[w][lane], x1 = src[w][lane + 64];
    float s = x0 + x1, sq = x0 * x0 + x1 * x1;
    #pragma unroll
    for (int m = 1; m < 64; m <<= 1) { s += __shfl_xor(s, m); sq += __shfl_xor(sq, m); }
    float mn = s * 0.0078125f;
    float vr = sq * 0.0078125f - mn * mn;
    float rs = rsqrtf(vr + 1e-5f);
    sh->a16[w][lane]      = (_Float16)((x0 - mn) * rs * wv[lane]      + bv[lane]);
    sh->a16[w][lane + 64] = (_Float16)((x1 - mn) * rs * wv[lane + 64] + bv[lane + 64]);
  } else {
    sh->a16[w][lane] = (_Float16)0.f;
    sh->a16[w][lane + 64] = (_Float16)0.f;
  }
}

__global__ __launch_bounds__(1024, 4) void slot_attn_kernel(P2Args P) {
  __shared__ SH sh;
  const int tid = threadIdx.x;
  const int w = tid >> 6, lane = tid & 63, quad = lane >> 4, l15 = lane & 15;
  const int b = blockIdx.x & 15;       // batch
  const int g = blockIdx.x >> 4;       // n-group (0..7) -> same XCD for fixed b
  const int n0 = g * 128;
  int* ctrb = P.ctr + b;
  int bar_phase = 0;

  for (int i = tid; i < 384; i += 1024) { sh.bih[i] = P.bih[i]; sh.bhh[i] = P.bhh[i]; }
  for (int i = tid; i < 256; i += 1024) sh.mb1[i] = P.mb1[i];
  for (int i = tid; i < 512; i += 1024) sh.fb1[i] = P.fb1[i];
  if (tid < 128) {
    sh.mb2[tid]  = P.mb2[tid];  sh.fb2[tid]  = P.fb2[tid];
    sh.lnsw[tid] = P.lnsw[tid]; sh.lnsb[tid] = P.lnsb[tid];
    sh.lnmw[tid] = P.lnmw[tid]; sh.lnmb[tid] = P.lnmb[tid];
    sh.pl1w[tid] = P.pl1w[tid]; sh.pl1b[tid] = P.pl1b[tid];
    sh.pl2w[tid] = P.pl2w[tid]; sh.pl2b[tid] = P.pl2b[tid];
    sh.plfw[tid] = P.plfw[tid]; sh.plfb[tid] = P.plfb[tid];
  }
  {
    int kk = tid >> 7, s = tid & 127;
    sh.slots[kk][s] = P.mu[s] + expf(P.lsig[s]) * P.noise[(b * 8 + kk) * 128 + s];
  }
  __syncthreads();

  for (int t = 0; t < 12; t++) {
    const _Float16* kt = P.kbuf + ((size_t)(b * 12 + t)) * 1024 * 128 + (size_t)n0 * 128;
    const _Float16* vt = P.vT   + ((size_t)(b * 12 + t)) * 128 * 1024 + n0;
    // ---- stage k/v slice into LDS (32 KB each)
    {
      int r = tid >> 4, c8 = (tid & 15) * 8;
      #pragma unroll
      for (int p = 0; p < 2; p++) {
        int row = p * 64 + r;
        *(half8*)&sh.k_lds[row][c8] = *(const half8*)(kt + (size_t)row * 128 + c8);
        *(half8*)&sh.v_lds[row][c8] = *(const half8*)(vt + (size_t)row * 1024 + c8);
      }
    }
    if (tid < 128) sh.vsum[tid] = 0.f;
    __syncthreads();
    // ---- vsum partial over local n from v_lds
    {
      int s = tid >> 3, j = tid & 7;
      float a = 0.f;
      #pragma unroll
      for (int e = 0; e < 16; e++) a += (float)sh.v_lds[s][j * 16 + e];
      atomicAdd(&sh.vsum[s], a);
    }
    __syncthreads();
    if (tid < 128)
      __hip_atomic_store(&P.vs_p[(b * 8 + g) * 128 + tid], sh.vsum[tid],
                         __ATOMIC_RELAXED, __HIP_MEMORY_SCOPE_AGENT);

    for (int it = 0; it < 3; it++) {
      const int par = (t * 3 + it) & 1;
      float* updg = P.upd_p + ((size_t)(par * 16 + b) * 8 + g) * 1024;
      float* colg = P.col_p + ((size_t)(par * 16 + b) * 8 + g) * 8;
      // ---- ph1: LN(slots) -> a16 rows 0..7; h16 = f16(slots)
      if (w < 8) {
        float x0 = sh.slots[w][lane], x1 = sh.slots[w][lane + 64];
        sh.h16[w][lane] = (_Float16)x0; sh.h16[w][lane + 64] = (_Float16)x1;
        float s = x0 + x1, sq = x0 * x0 + x1 * x1;
        #pragma unroll
        for (int m = 1; m < 64; m <<= 1) { s += __shfl_xor(s, m); sq += __shfl_xor(sq, m); }
        float mn = s * 0.0078125f;
        float vr = sq * 0.0078125f - mn * mn;
        float rs = rsqrtf(vr + 1e-5f);
        sh.a16[w][lane]      = (_Float16)((x0 - mn) * rs * sh.lnsw[lane]      + sh.lnsb[lane]);
        sh.a16[w][lane + 64] = (_Float16)((x1 - mn) * rs * sh.lnsw[lane + 64] + sh.lnsb[lane + 64]);
      } else {
        sh.h16[w][lane] = (_Float16)0.f; sh.h16[w][lane + 64] = (_Float16)0.f;
        sh.a16[w][lane] = (_Float16)0.f; sh.a16[w][lane + 64] = (_Float16)0.f;
      }
      if (tid < 8) sh.colsum[tid] = 0.f;
      __syncthreads();
      // ---- ph2: w<8: q = y @ Wq -> qT ; w>=8: gh tiles 0,1 (of 3), direct
      if (w < 8) {
        floatx4 acc = (floatx4){0.f, 0.f, 0.f, 0.f};
        const _Float16* ar = &sh.a16[l15][quad * 8];
        const _Float16* br = P.WqT + (size_t)(w * 16 + l15) * 128 + quad * 8;
        #pragma unroll
        for (int ks = 0; ks < 4; ks++)
          acc = MFMA_F16(*(const half8*)(ar + ks * 32), *(const half8*)(br + ks * 32), acc);
        #pragma unroll
        for (int r = 0; r < 4; r++)
          sh.u.sa.qT[quad * 4 + r][w * 16 + l15] = (_Float16)acc[r];
      } else {
        const int idx8 = w - 8;
        const _Float16* ar = &sh.h16[l15][quad * 8];
        #pragma unroll
        for (int tt = 0; tt < 2; tt++) {
          int ct = idx8 + tt * 8;
          const _Float16* Bg = P.Whh + (size_t)(ct * 16 + l15) * 128 + quad * 8;
          floatx4 acc = (floatx4){0.f, 0.f, 0.f, 0.f};
          #pragma unroll
          for (int ks = 0; ks < 4; ks++)
            acc = MFMA_F16(*(const half8*)(ar + ks * 32), *(const half8*)(Bg + ks * 32), acc);
          int col = ct * 16 + l15;
          #pragma unroll
          for (int r = 0; r < 4; r++) {
            int slot = quad * 4 + r;
            if (slot < 8) sh.gh[slot][col] = acc[r] + sh.bhh[col];
          }
        }
      }
      __syncthreads();
      // ---- ph3: w<8: logits+softmax+colsum; w>=8: gh tile 2, direct
      if (w < 8) {
        int nloc0 = w * 16;
        floatx4 acc = (floatx4){0.f, 0.f, 0.f, 0.f};
        const _Float16* ar = &sh.k_lds[nloc0 + l15][quad * 8];
        const _Float16* br = &sh.u.sa.qT[l15][quad * 8];
        #pragma unroll
        for (int ks = 0; ks < 4; ks++)
          acc = MFMA_F16(*(const half8*)(ar + ks * 32), *(const half8*)(br + ks * 32), acc);
        float cs = 0.f;
        #pragma unroll
        for (int r = 0; r < 4; r++) {
          float v = (l15 < 8) ? acc[r] : -3.0e38f;
          float mx = v;
          mx = fmaxf(mx, __shfl_xor(mx, 1, 16));
          mx = fmaxf(mx, __shfl_xor(mx, 2, 16));
          mx = fmaxf(mx, __shfl_xor(mx, 4, 16));
          mx = fmaxf(mx, __shfl_xor(mx, 8, 16));
          float pv = (l15 < 8) ? expf(v - mx) : 0.f;
          float ss = pv;
          ss += __shfl_xor(ss, 1, 16); ss += __shfl_xor(ss, 2, 16);
          ss += __shfl_xor(ss, 4, 16); ss += __shfl_xor(ss, 8, 16);
          float pn = pv / ss;
          cs += pn;
          int nloc = nloc0 + quad * 4 + r;
          sh.u.sa.attnT[l15][nloc] = (_Float16)pn;
          if (it == 2 && l15 < 8)
            P.out_attn[((size_t)(b * 12 + t) * 1024 + n0 + nloc) * 8 + l15] = pn;
        }
        cs += __shfl_xor(cs, 16); cs += __shfl_xor(cs, 32);
        if (lane < 8) atomicAdd(&sh.colsum[lane], cs);
      } else {
        const int idx8 = w - 8;
        int ct = idx8 + 16;
        const _Float16* ar = &sh.h16[l15][quad * 8];
        const _Float16* Bg = P.Whh + (size_t)(ct * 16 + l15) * 128 + quad * 8;
        floatx4 acc = (floatx4){0.f, 0.f, 0.f, 0.f};
        #pragma unroll
        for (int ks = 0; ks < 4; ks++)
          acc = MFMA_F16(*(const half8*)(ar + ks * 32), *(const half8*)(Bg + ks * 32), acc);
        int col = ct * 16 + l15;
        #pragma unroll
        for (int r = 0; r < 4; r++) {
          int slot = quad * 4 + r;
          if (slot < 8) sh.gh[slot][col] = acc[r] + sh.bhh[col];
        }
      }
      __syncthreads();
      // ---- ph4: w<8: partial updates = P^T @ v over local n -> global
      if (w < 8) {
        floatx4 acc = (floatx4){0.f, 0.f, 0.f, 0.f};
        const _Float16* ar = &sh.u.sa.attnT[l15][quad * 8];
        const _Float16* br = &sh.v_lds[w * 16 + l15][quad * 8];
        #pragma unroll
        for (int ks = 0; ks < 4; ks++)
          acc = MFMA_F16(*(const half8*)(ar + ks * 32), *(const half8*)(br + ks * 32), acc);
        int scol = w * 16 + l15;
        #pragma unroll
        for (int r = 0; r < 4; r++) {
          int slot = quad * 4 + r;
          if (slot < 8)
            __hip_atomic_store(&updg[slot * 128 + scol], acc[r],
                               __ATOMIC_RELAXED, __HIP_MEMORY_SCOPE_AGENT);
        }
      }
      if (tid < 8)
        __hip_atomic_store(&colg[tid], sh.colsum[tid],
                           __ATOMIC_RELAXED, __HIP_MEMORY_SCOPE_AGENT);
      // ---- 8-block barrier
      bar_phase++;
      group_barrier(ctrb, 8 * bar_phase);
      // ---- reduce partials; fold eps renorm -> a16 rows 0..7
      {
        int slot = tid >> 7, scol = tid & 127;
        const float* up = P.upd_p + (size_t)(par * 16 + b) * 8 * 1024 + slot * 128 + scol;
        float sum = 0.f;
        #pragma unroll
        for (int gg = 0; gg < 8; gg++)
          sum += __hip_atomic_load((float*)(up + gg * 1024),
                                   __ATOMIC_RELAXED, __HIP_MEMORY_SCOPE_AGENT);
        float csum = 0.f;
        if (tid < 8) {
          const float* cp = P.col_p + (size_t)(par * 16 + b) * 8 * 8 + tid;
          #pragma unroll
          for (int gg = 0; gg < 8; gg++)
            csum += __hip_atomic_load((float*)(cp + gg * 8),
                                      __ATOMIC_RELAXED, __HIP_MEMORY_SCOPE_AGENT);
        }
        float vtot = 0.f;
        if (it == 0 && tid < 128) {
          const float* vp = P.vs_p + b * 8 * 128 + tid;
          #pragma unroll
          for (int gg = 0; gg < 8; gg++)
            vtot += __hip_atomic_load((float*)(vp + gg * 128),
                                      __ATOMIC_RELAXED, __HIP_MEMORY_SCOPE_AGENT);
        }
        __syncthreads();
        if (tid < 8) sh.colsum[tid] = csum;
        if (it == 0 && tid < 128) sh.vsum[tid] = vtot;
        __syncthreads();
        float upd = (sum + 1e-8f * sh.vsum[scol]) / (sh.colsum[slot] + 1024.f * 1e-8f);
        sh.a16[slot][scol] = (_Float16)upd;
      }
      __syncthreads();
      // ---- GRU gi: all waves tile ct=w; w<8 also ct=16+w (direct reads)
      {
        const _Float16* ar = &sh.a16[l15][quad * 8];
        const _Float16* Bg = P.Wih + (size_t)(w * 16 + l15) * 128 + quad * 8;
        floatx4 acc = (floatx4){0.f, 0.f, 0.f, 0.f};
        #pragma unroll
        for (int ks = 0; ks < 4; ks++)
          acc = MFMA_F16(*(const half8*)(ar + ks * 32), *(const half8*)(Bg + ks * 32), acc);
        int col = w * 16 + l15;
        #pragma unroll
        for (int r = 0; r < 4; r++) {
          int slot = quad * 4 + r;
          if (slot < 8) sh.gi[slot][col] = acc[r] + sh.bih[col];
        }
        if (w < 8) {
          int col2 = (16 + w) * 16 + l15;
          const _Float16* Bg2 = P.Wih + (size_t)((16 + w) * 16 + l15) * 128 + quad * 8;
          floatx4 acc2 = (floatx4){0.f, 0.f, 0.f, 0.f};
          #pragma unroll
          for (int ks = 0; ks < 4; ks++)
            acc2 = MFMA_F16(*(const half8*)(ar + ks * 32), *(const half8*)(Bg2 + ks * 32), acc2);
          #pragma unroll
          for (int r = 0; r < 4; r++) {
            int slot = quad * 4 + r;
            if (slot < 8) sh.gi[slot][col2] = acc2[r] + sh.bih[col2];
          }
        }
      }
      __syncthreads();
      // ---- gates + LN fused (waves 0-7); writes slots + a16 (lnm / pl1)
      if (w < 8) {
        float h0 = sh.slots[w][lane], h1 = sh.slots[w][lane + 64];
        float r0 = 1.f / (1.f + expf(-(sh.gi[w][lane]       + sh.gh[w][lane])));
        float z0 = 1.f / (1.f + expf(-(sh.gi[w][128 + lane] + sh.gh[w][128 + lane])));
        float n0v = tanhf(sh.gi[w][256 + lane] + r0 * sh.gh[w][256 + lane]);
        float x0 = (1.f - z0) * n0v + z0 * h0;
        int l64 = lane + 64;
        float r1 = 1.f / (1.f + expf(-(sh.gi[w][l64]       + sh.gh[w][l64])));
        float z1 = 1.f / (1.f + expf(-(sh.gi[w][128 + l64] + sh.gh[w][128 + l64])));
        float n1v = tanhf(sh.gi[w][256 + l64] + r1 * sh.gh[w][256 + l64]);
        float x1 = (1.f - z1) * n1v + z1 * h1;
        sh.slots[w][lane] = x0; sh.slots[w][lane + 64] = x1;
        if (it == 2 && g == 0) {
          P.out_slots[((size_t)(b * 12 + t) * 8 + w) * 128 + lane]      = x0;
          P.out_slots[((size_t)(b * 12 + t) * 8 + w) * 128 + lane + 64] = x1;
        }
        // fused LN -> a16 (lnm for MLP iters, pl1 for predictor entry)
        const float* wv = (it < 2) ? sh.lnmw : sh.pl1w;
        const float* bv = (it < 2) ? sh.lnmb : sh.pl1b;
        float s = x0 + x1, sq = x0 * x0 + x1 * x1;
        #pragma unroll
        for (int m = 1; m < 64; m <<= 1) { s += __shfl_xor(s, m); sq += __shfl_xor(sq, m); }
        float mn = s * 0.0078125f;
        float vr = sq * 0.0078125f - mn * mn;
        float rs = rsqrtf(vr + 1e-5f);
        sh.a16[w][lane]      = (_Float16)((x0 - mn) * rs * wv[lane]      + bv[lane]);
        sh.a16[w][lane + 64] = (_Float16)((x1 - mn) * rs * wv[lane + 64] + bv[lane + 64]);
      }
      __syncthreads();
      // ---- residual MLP (iters 0,1)
      if (it < 2) {
        {
          floatx4 acc = (floatx4){0.f, 0.f, 0.f, 0.f};
          const _Float16* ar = &sh.a16[l15][quad * 8];
          const _Float16* br = P.W1T + (size_t)(w * 16 + l15) * 128 + quad * 8;
          #pragma unroll
          for (int ks = 0; ks < 4; ks++)
            acc = MFMA_F16(*(const half8*)(ar + ks * 32), *(const half8*)(br + ks * 32), acc);
          int col = w * 16 + l15;
          #pragma unroll
          for (int r = 0; r < 4; r++) {
            int slot = quad * 4 + r;
            if (slot < 8) sh.u.mlp.m16[slot][col] = (_Float16)fmaxf(acc[r] + sh.mb1[col], 0.f);
            else          sh.u.mlp.m16[slot][col] = (_Float16)0.f;
          }
        }
        __syncthreads();
        if (w < 8) {
          floatx4 acc = (floatx4){0.f, 0.f, 0.f, 0.f};
          const _Float16* ar = &sh.u.mlp.m16[l15][quad * 8];
          const _Float16* br = P.W2T + (size_t)(w * 16 + l15) * 256 + quad * 8;
          #pragma unroll
          for (int ks = 0; ks < 8; ks++)
            acc = MFMA_F16(*(const half8*)(ar + ks * 32), *(const half8*)(br + ks * 32), acc);
          int col = w * 16 + l15;
          #pragma unroll
          for (int r = 0; r < 4; r++) {
            int slot = quad * 4 + r;
            if (slot < 8) sh.slots[slot][col] += acc[r] + sh.mb2[col];
          }
        }
        __syncthreads();
      }
    } // it

    // ---- predictor (redundant, identical in all 8 blocks); a16 = LN_pl1(slots)
    // QKV: wave w does tile j=w (q/k direct); w<8 also pVT tile w (direct)
    {
      const _Float16* ar = &sh.a16[l15][quad * 8];
      int gg = w >> 3, ct = w & 7, col = ct * 16 + l15;
      const _Float16* Bg = (gg == 0 ? P.pQT : P.pKT) + (size_t)(ct * 16 + l15) * 128 + quad * 8;
      floatx4 acc = (floatx4){0.f, 0.f, 0.f, 0.f};
      #pragma unroll
      for (int ks = 0; ks < 4; ks++)
        acc = MFMA_F16(*(const half8*)(ar + ks * 32), *(const half8*)(Bg + ks * 32), acc);
      float scale = (gg == 0) ? 0.17677669529663687f : 1.f;
      float* dst = (gg == 0) ? &sh.u.mha.qh[0][0] : &sh.u.mha.kh[0][0];
      #pragma unroll
      for (int r = 0; r < 4; r++) {
        int slot = quad * 4 + r;
        if (slot < 8) dst[slot * 128 + col] = acc[r] * scale;
      }
      if (w < 8) {
        const _Float16* Bg2 = P.pVT + (size_t)(w * 16 + l15) * 128 + quad * 8;
        floatx4 a2 = (floatx4){0.f, 0.f, 0.f, 0.f};
        #pragma unroll
        for (int ks = 0; ks < 4; ks++)
          a2 = MFMA_F16(*(const half8*)(ar + ks * 32), *(const half8*)(Bg2 + ks * 32), a2);
        int colv = w * 16 + l15;
        #pragma unroll
        for (int r = 0; r < 4; r++) {
          int slot = quad * 4 + r;
          if (slot < 8) sh.u.mha.vh[slot][colv] = a2[r];
        }
      }
    }
    __syncthreads();
    if (tid < 256) {
      int h = tid >> 6, a = (tid >> 3) & 7, b2 = tid & 7;
      const float* qr = &sh.u.mha.qh[a][h * 32];
      const float* kr = &sh.u.mha.kh[b2][h * 32];
      float s = 0.f;
      #pragma unroll
      for (int d = 0; d < 32; d++) s += qr[d] * kr[d];
      sh.u.mha.sc[h][a][b2] = s;
    }
    __syncthreads();
    if (tid < 32) {
      int h = tid >> 3, a = tid & 7;
      float* p = sh.u.mha.sc[h][a];
      float mx = p[0];
      #pragma unroll
      for (int j = 1; j < 8; j++) mx = fmaxf(mx, p[j]);
      float e[8]; float ssum = 0.f;
      #pragma unroll
      for (int j = 0; j < 8; j++) { e[j] = expf(p[j] - mx); ssum += e[j]; }
      float inv = 1.f / ssum;
      #pragma unroll
      for (int j = 0; j < 8; j++) p[j] = e[j] * inv;
    }
    __syncthreads();
    {
      int a = tid >> 7, col = tid & 127, h = col >> 5;
      float acc = 0.f;
      #pragma unroll
      for (int b2 = 0; b2 < 8; b2++) acc += sh.u.mha.sc[h][a][b2] * sh.u.mha.vh[b2][col];
      sh.a16[a][col] = (_Float16)acc;
    }
    __syncthreads();
    if (w < 8) {       // s += o @ Wo
      floatx4 acc = (floatx4){0.f, 0.f, 0.f, 0.f};
      const _Float16* ar = &sh.a16[l15][quad * 8];
      const _Float16* br = P.pOT + (size_t)(w * 16 + l15) * 128 + quad * 8;
      #pragma unroll
      for (int ks = 0; ks < 4; ks++)
        acc = MFMA_F16(*(const half8*)(ar + ks * 32), *(const half8*)(br + ks * 32), acc);
      int col = w * 16 + l15;
      #pragma unroll
      for (int r = 0; r < 4; r++) {
        int slot = quad * 4 + r;
        if (slot < 8) sh.slots[slot][col] += acc[r];
      }
    }
    __syncthreads();
    ln_to_a16(&sh, sh.slots, sh.pl2w, sh.pl2b, w, lane);
    __syncthreads();
    for (int ct = w; ct < 32; ct += 16) {   // FFN1 + relu
      floatx4 acc = (floatx4){0.f, 0.f, 0.f, 0.f};
      const _Float16* ar = &sh.a16[l15][quad * 8];
      const _Float16* br = P.pF1T + (size_t)(ct * 16 + l15) * 128 + quad * 8;
      #pragma unroll
      for (int ks = 0; ks < 4; ks++)
        acc = MFMA_F16(*(const half8*)(ar + ks * 32), *(const half8*)(br + ks * 32), acc);
      int col = ct * 16 + l15;
      #pragma unroll
      for (int r = 0; r < 4; r++) {
        int slot = quad * 4 + r;
        if (slot < 8) sh.u.ffn.f16[slot][col] = (_Float16)fmaxf(acc[r] + sh.fb1[col], 0.f);
        else          sh.u.ffn.f16[slot][col] = (_Float16)0.f;
      }
    }
    __syncthreads();
    if (w < 8) {       // FFN2 + residual
      floatx4 acc = (floatx4){0.f, 0.f, 0.f, 0.f};
      const _Float16* ar = &sh.u.ffn.f16[l15][quad * 8];
      const _Float16* br = P.pF2T + (size_t)(w * 16 + l15) * 512 + quad * 8;
      #pragma unroll 4
      for (int ks = 0; ks < 16; ks++)
        acc = MFMA_F16(*(const half8*)(ar + ks * 32), *(const half8*)(br + ks * 32), acc);
      int col = w * 16 + l15;
      #pragma unroll
      for (int r = 0; r < 4; r++) {
        int slot = quad * 4 + r;
        if (slot < 8) sh.slots[slot][col] += acc[r] + sh.fb2[col];
      }
    }
    __syncthreads();
    if (w < 8) {       // final LN -> carry
      float x0 = sh.slots[w][lane], x1 = sh.slots[w][lane + 64];
      float s = x0 + x1, sq = x0 * x0 + x1 * x1;
      #pragma unroll
      for (int m = 1; m < 64; m <<= 1) { s += __shfl_xor(s, m); sq += __shfl_xor(sq, m); }
      float mn = s * 0.0078125f;
      float vr = sq * 0.0078125f - mn * mn;
      float rs = rsqrtf(vr + 1e-5f);
      sh.slots[w][lane]      = (x0 - mn) * rs * sh.plfw[lane]      + sh.plfb[lane];
      sh.slots[w][lane + 64] = (x1 - mn) * rs * sh.plfw[lane + 64] + sh.plfb[lane + 64];
    }
    __syncthreads();
  } // t
}

// ---------------------------------------------------------------------------
extern "C" void kernel_launch(void* const* d_in, const int* in_sizes, int n_in,
                              void* d_out, int out_size, void* d_ws, size_t ws_size,
                              hipStream_t stream) {
  const float* inp   = (const float*)d_in[0];
  const float* noise = (const float*)d_in[1];
  const float* mu    = (const float*)d_in[2];
  const float* lsig  = (const float*)d_in[3];
  const float* lniw  = (const float*)d_in[4];
  const float* lnib  = (const float*)d_in[5];
  const float* lnsw  = (const float*)d_in[6];
  const float* lnsb  = (const float*)d_in[7];
  const float* lnmw  = (const float*)d_in[8];
  const float* lnmb  = (const float*)d_in[9];
  const float* Wq    = (const float*)d_in[10];
  const float* Wk    = (const float*)d_in[11];
  const float* Wv    = (const float*)d_in[12];
  const float* gWih  = (const float*)d_in[13];
  const float* gWhh  = (const float*)d_in[14];
  const float* gbih  = (const float*)d_in[15];
  const float* gbhh  = (const float*)d_in[16];
  const float* mW1   = (const float*)d_in[17];
  const float* mb1   = (const float*)d_in[18];
  const float* mW2   = (const float*)d_in[19];
  const float* mb2   = (const float*)d_in[20];
  const float* pl1w  = (const float*)d_in[21];
  const float* pl1b  = (const float*)d_in[22];
  const float* pWq   = (const float*)d_in[23];
  const float* pWk   = (const float*)d_in[24];
  const float* pWv   = (const float*)d_in[25];
  const float* pWo   = (const float*)d_in[26];
  const float* pl2w  = (const float*)d_in[27];
  const float* pl2b  = (const float*)d_in[28];
  const float* pf1   = (const float*)d_in[29];
  const float* pfb1  = (const float*)d_in[30];
  const float* pf2   = (const float*)d_in[31];
  const float* pfb2  = (const float*)d_in[32];
  const float* plfw  = (const float*)d_in[33];
  const float* plfb  = (const float*)d_in[34];

  // workspace layout (f16 elements); ~101.5 MB + ~0.6 MB partials
  _Float16* p   = (_Float16*)d_ws;
  _Float16* kbuf = p;  p += 25165824;
  _Float16* vT   = p;  p += 25165824;
  _Float16* WT   = p;  p += 65536;
  _Float16* WqT  = p;  p += 16384;
  _Float16* Wih  = p;  p += 49152;
  _Float16* Whh  = p;  p += 49152;
  _Float16* W1T  = p;  p += 32768;
  _Float16* W2T  = p;  p += 32768;
  _Float16* pQT  = p;  p += 16384;
  _Float16* pKT  = p;  p += 16384;
  _Float16* pVT  = p;  p += 16384;
  _Float16* pOT  = p;  p += 16384;
  _Float16* pF1T = p;  p += 65536;
  _Float16* pF2T = p;  p += 65536;
  float* fb   = (float*)p;
  float* upd_p = fb;  fb += 2 * 16 * 8 * 1024;   // 131072
  float* col_p = fb;  fb += 2 * 16 * 8 * 8;      // 2048
  float* vs_p  = fb;  fb += 16 * 8 * 128;        // 16384
  int*   ctr   = (int*)fb;                       // 16

  const float kscale = 0.08838834764831845f;  // S^-0.5, S=128
  init_ctr_kernel<<<1, 64, 0, stream>>>(ctr);

  PrepJobs J;
  const float* srcs[13] = {Wk, Wv, Wq, gWih, gWhh, mW1, mW2, pWq, pWk, pWv, pWo, pf1, pf2};
  _Float16* dsts[13]    = {WT, WT + 32768, WqT, Wih, Whh, W1T, W2T, pQT, pKT, pVT, pOT, pF1T, pF2T};
  int Ins[13]    = {256, 256, 128, 49152, 49152, 128, 256, 128, 128, 128, 128, 128, 512};
  int Outs[13]   = {128, 128, 128, 1, 1, 256, 128, 128, 128, 128, 128, 512, 128};
  int elemss[13] = {32768, 32768, 16384, 49152, 49152, 32768, 32768, 16384, 16384, 16384, 16384, 65536, 65536};
  int doTs[13]   = {1, 1, 1, 0, 0, 1, 1, 1, 1, 1, 1, 1, 1};
  float scales[13] = {kscale, 1.f, 1.f, 1.f, 1.f, 1.f, 1.f, 1.f, 1.f, 1.f, 1.f, 1.f, 1.f};
  for (int j = 0; j < 13; j++) {
    J.src[j] = srcs[j]; J.dst[j] = dsts[j]; J.In[j] = Ins[j]; J.Out[j] = Outs[j];
    J.elems[j] = elemss[j]; J.doT[j] = doTs[j]; J.scale[j] = scales[j];
  }
  dim3 gp(256, 13, 1);
  prep_all_kernel<<<gp, 256, 0, stream>>>(J);

  dim3 g1(1536, 2, 1);
  gemm_kv_kernel<<<g1, 256, 0, stream>>>(inp, lniw, lnib, WT, kbuf, vT);

  P2Args a;
  a.kbuf = kbuf; a.vT = vT;
  a.WqT = WqT; a.Wih = Wih; a.Whh = Whh; a.W1T = W1T; a.W2T = W2T;
  a.pQT = pQT; a.pKT = pKT; a.pVT = pVT; a.pOT = pOT; a.pF1T = pF1T; a.pF2T = pF2T;
  a.noise = noise; a.mu = mu; a.lsig = lsig;
  a.lnsw = lnsw; a.lnsb = lnsb; a.lnmw = lnmw; a.lnmb = lnmb;
  a.bih = gbih; a.bhh = gbhh; a.mb1 = mb1; a.mb2 = mb2;
  a.pl1w = pl1w; a.pl1b = pl1b; a.pl2w = pl2w; a.pl2b = pl2b;
  a.fb1 = pfb1; a.fb2 = pfb2; a.plfw = plfw; a.plfb = plfb;
  a.out_slots = (float*)d_out;
  a.out_attn  = (float*)d_out + 196608;
  a.upd_p = upd_p; a.col_p = col_p; a.vs_p = vs_p; a.ctr = ctr;

  slot_attn_kernel<<<128, 1024, 0, stream>>>(a);
}

// Round 5
// 1243.721 us; speedup vs baseline: 1.4214x; 1.0897x over previous
//
#include <hip/hip_runtime.h>
#include <hip/hip_bf16.h>

typedef _Float16 half8 __attribute__((ext_vector_type(8)));
typedef float floatx4 __attribute__((ext_vector_type(4)));

#define MFMA_F16(a, b, c) __builtin_amdgcn_mfma_f32_16x16x32_f16((a), (b), (c), 0, 0, 0)

// ---------------------------------------------------------------------------
// fused prep: 11 f32->f16 (optional transpose, scale) jobs in one launch.
// ---------------------------------------------------------------------------
struct PrepJobs {
  const float* src[11];
  _Float16* dst[11];
  int In[11], Out[11], elems[11], doT[11];
  float scale[11];
};

__global__ void prep_all_kernel(PrepJobs J) {
  int j = blockIdx.y;
  int idx = blockIdx.x * 256 + threadIdx.x;
  if (idx >= J.elems[j]) return;
  float v;
  if (J.doT[j]) { int o = idx / J.In[j], i = idx - o * J.In[j]; v = J.src[j][i * J.Out[j] + o]; }
  else          { v = J.src[j][idx]; }
  J.dst[j][idx] = (_Float16)(v * J.scale[j]);
}

// W~T[s][i] = kscale * sum_o Wk[i][o] * Wq[s][o]   (folds Wq into the k GEMM:
// logits = k @ qT = (xhat @ Wk Wq^T) @ y^T, so phase-2 needs no q GEMM at all)
__global__ void prep_wtilde_kernel(const float* __restrict__ Wk, const float* __restrict__ Wq,
                                   _Float16* __restrict__ WT, float scale) {
  int idx = blockIdx.x * 256 + threadIdx.x;   // 32768 = 128 s * 256 i
  int s = idx >> 8, i = idx & 255;
  const float* wk = Wk + (size_t)i * 128;
  const float* wq = Wq + (size_t)s * 128;
  float acc = 0.f;
  #pragma unroll 4
  for (int o = 0; o < 128; o++) acc += wk[o] * wq[o];
  WT[idx] = (_Float16)(acc * scale);
}

__global__ void init_ctr_kernel(int* __restrict__ ctr) {
  ctr[threadIdx.x] = 0;   // 1024 ints (16 batches x 64-int stride = 256B pad)
}

// ---------------------------------------------------------------------------
// phase 1: fused LN + dual GEMM.  grid (1536, 2), 256 threads. (unchanged)
// y==0 half of WT now holds W~T (k-tilde weights), y==1 holds WvT.
// ---------------------------------------------------------------------------
__global__ __launch_bounds__(256) void gemm_kv_kernel(
    const float* __restrict__ x, const float* __restrict__ lnw_g,
    const float* __restrict__ lnb_g, const _Float16* __restrict__ WT,
    _Float16* __restrict__ kout, _Float16* __restrict__ vTout) {
  __shared__ union {
    struct { _Float16 A[128][72]; _Float16 B[128][72]; } s;
    _Float16 C[128][136];
  } u;
  __shared__ float s_mean[128], s_rstd[128], s_red[256][2], s_lnw[256], s_lnb[256];

  const int tid = threadIdx.x;
  const int bx = blockIdx.x, y = blockIdx.y;
  const size_t r0 = (size_t)bx * 128;
  const int w = tid >> 6, lane = tid & 63, quad = lane >> 4, l15 = lane & 15;

  s_lnw[tid] = lnw_g[tid];
  s_lnb[tid] = lnb_g[tid];
  {
    int row = tid >> 1, half = tid & 1;
    const float* p = x + (r0 + row) * 256 + half * 128;
    float s = 0.f, sq = 0.f;
    for (int i = 0; i < 32; i++) {
      float4 d = ((const float4*)p)[i];
      s += d.x + d.y + d.z + d.w;
      sq += d.x * d.x + d.y * d.y + d.z * d.z + d.w * d.w;
    }
    s_red[tid][0] = s; s_red[tid][1] = sq;
  }
  __syncthreads();
  if (tid < 128) {
    float s  = s_red[2 * tid][0] + s_red[2 * tid + 1][0];
    float sq = s_red[2 * tid][1] + s_red[2 * tid + 1][1];
    float m = s * (1.f / 256.f);
    float v = sq * (1.f / 256.f) - m * m;
    s_mean[tid] = m; s_rstd[tid] = rsqrtf(v + 1e-5f);
  }

  floatx4 acc[2][8];
  for (int rt = 0; rt < 2; rt++)
    for (int ct = 0; ct < 8; ct++) acc[rt][ct] = (floatx4){0.f, 0.f, 0.f, 0.f};

  for (int c = 0; c < 4; c++) {
    __syncthreads();
    for (int i = 0; i < 4; i++) {
      int g = tid + 256 * i;
      int row = g >> 3, c8 = g & 7;
      int col0 = c * 64 + c8 * 8;
      const float* p = x + (r0 + row) * 256 + col0;
      float4 d0 = ((const float4*)p)[0];
      float4 d1 = ((const float4*)p)[1];
      float f[8] = {d0.x, d0.y, d0.z, d0.w, d1.x, d1.y, d1.z, d1.w};
      float m = s_mean[row], rs = s_rstd[row];
      half8 hv;
      #pragma unroll
      for (int j = 0; j < 8; j++)
        hv[j] = (_Float16)((f[j] - m) * rs * s_lnw[col0 + j] + s_lnb[col0 + j]);
      *(half8*)&u.s.A[row][c8 * 8] = hv;
      *(half8*)&u.s.B[row][c8 * 8] = *(const half8*)(WT + (size_t)(y * 128 + row) * 256 + col0);
    }
    __syncthreads();
    #pragma unroll
    for (int ks = 0; ks < 2; ks++) {
      half8 af[2];
      af[0] = *(const half8*)&u.s.A[(2 * w) * 16 + l15][ks * 32 + quad * 8];
      af[1] = *(const half8*)&u.s.A[(2 * w + 1) * 16 + l15][ks * 32 + quad * 8];
      #pragma unroll
      for (int ct = 0; ct < 8; ct++) {
        half8 bf = *(const half8*)&u.s.B[ct * 16 + l15][ks * 32 + quad * 8];
        acc[0][ct] = MFMA_F16(af[0], bf, acc[0][ct]);
        acc[1][ct] = MFMA_F16(af[1], bf, acc[1][ct]);
      }
    }
  }

  const size_t bt = (size_t)(bx >> 3);
  const int n0loc = (bx & 7) * 128;
  if (y == 0) {
    for (int rt = 0; rt < 2; rt++)
      for (int ct = 0; ct < 8; ct++)
        #pragma unroll
        for (int r = 0; r < 4; r++) {
          size_t row = r0 + (2 * w + rt) * 16 + quad * 4 + r;
          kout[row * 128 + ct * 16 + l15] = (_Float16)acc[rt][ct][r];
        }
  } else {
    __syncthreads();
    for (int rt = 0; rt < 2; rt++)
      for (int ct = 0; ct < 8; ct++)
        #pragma unroll
        for (int r = 0; r < 4; r++)
          u.C[(2 * w + rt) * 16 + quad * 4 + r][ct * 16 + l15] = (_Float16)acc[rt][ct][r];
    __syncthreads();
    int s = tid >> 1, hf = tid & 1;
    for (int j = 0; j < 8; j++) {
      int nb = hf * 64 + j * 8;
      half8 tmp;
      #pragma unroll
      for (int e = 0; e < 8; e++) tmp[e] = u.C[nb + e][s];
      *(half8*)(vTout + (bt * 128 + s) * 1024 + n0loc + nb) = tmp;
    }
  }
}

// ---------------------------------------------------------------------------
// phase 2: slot-attention scan. grid 128 (= 16 batches x 8 n-groups), 1024 thr.
// Round-5: ctr padded to 256B/batch (kills cross-XCD line bouncing on the
// barrier); col_p padded to 256B/group; k~ fold removes the q GEMM stage;
// reduce phase self-computes csum/vsum (2 syncs removed); predictor mha
// scores+softmax+PV fused into one wave-per-head stage.
// ---------------------------------------------------------------------------
struct P2Args {
  const _Float16 *kbuf, *vT;
  const _Float16 *Wih, *Whh, *W1T, *W2T;
  const _Float16 *pQT, *pKT, *pVT, *pOT, *pF1T, *pF2T;
  const float *noise, *mu, *lsig;
  const float *lnsw, *lnsb, *lnmw, *lnmb;
  const float *bih, *bhh, *mb1, *mb2;
  const float *pl1w, *pl1b, *pl2w, *pl2b, *fb1, *fb2, *plfw, *plfb;
  float *out_slots, *out_attn;
  float *upd_p;   // [2][16][8][8*128]
  float *col_p;   // [2][16][8][64]  (8 used, 256B padded)
  float *vs_p;    // [16][8][128]
  int   *ctr;     // [16][64]        (1 used, 256B padded)
};

struct SH {
  _Float16 k_lds[128][136];   // k~ slice [n_local][s]
  _Float16 v_lds[128][136];   // v slice [s][n_local]
  float slots[8][128];
  _Float16 a16[16][136];
  _Float16 h16[16][136];
  float gi[8][384];
  float gh[8][384];
  union {
    struct { _Float16 qT[16][136]; _Float16 attnT[16][136]; } sa;
    struct { _Float16 m16[16][264]; } mlp;
    struct { float qh[8][128]; float kh[8][128]; float vh[8][128]; float sc[4][8][8]; } mha;
    struct { _Float16 f16[16][520]; } ffn;
  } u;
  float colsum[8];
  float vsum[128];
  float bih[384], bhh[384], mb1[256], mb2[128], fb1[512], fb2[128];
  float lnsw[128], lnsb[128], lnmw[128], lnmb[128];
  float pl1w[128], pl1b[128], pl2w[128], pl2b[128], plfw[128], plfb[128];
};

__device__ __forceinline__ void group_barrier(int* ctr, int target) {
  __syncthreads();   // drains vmcnt: all agent-scope stores complete
  if (threadIdx.x == 0) {
    __hip_atomic_fetch_add(ctr, 1, __ATOMIC_ACQ_REL, __HIP_MEMORY_SCOPE_AGENT);
    while (__hip_atomic_load(ctr, __ATOMIC_ACQUIRE, __HIP_MEMORY_SCOPE_AGENT) < target)
      __builtin_amdgcn_s_sleep(1);
  }
  __syncthreads();
}

__device__ __forceinline__ void ln_to_a16(SH* sh, const float (*src)[128],
                                          const float* wv, const float* bv,
                                          int w, int lane) {
  if (w < 8) {
    float x0 = src[w][lane], x1 = src[w][lane + 64];
    float s = x0 + x1, sq = x0 * x0 + x1 * x1;
    #pragma unroll
    for (int m = 1; m < 64; m <<= 1) { s += __shfl_xor(s, m); sq += __shfl_xor(sq, m); }
    float mn = s * 0.0078125f;
    float vr = sq * 0.0078125f - mn * mn;
    float rs = rsqrtf(vr + 1e-5f);
    sh->a16[w][lane]      = (_Float16)((x0 - mn) * rs * wv[lane]      + bv[lane]);
    sh->a16[w][lane + 64] = (_Float16)((x1 - mn) * rs * wv[lane + 64] + bv[lane + 64]);
  } else {
    sh->a16[w][lane] = (_Float16)0.f;
    sh->a16[w][lane + 64] = (_Float16)0.f;
  }
}

__global__ __launch_bounds__(1024, 4) void slot_attn_kernel(P2Args P) {
  __shared__ SH sh;
  const int tid = threadIdx.x;
  const int w = tid >> 6, lane = tid & 63, quad = lane >> 4, l15 = lane & 15;
  const int b = blockIdx.x & 15;       // batch
  const int g = blockIdx.x >> 4;       // n-group (0..7)
  const int n0 = g * 128;
  int* ctrb = P.ctr + b * 64;          // 256B-padded counter
  int bar_phase = 0;

  for (int i = tid; i < 384; i += 1024) { sh.bih[i] = P.bih[i]; sh.bhh[i] = P.bhh[i]; }
  for (int i = tid; i < 256; i += 1024) sh.mb1[i] = P.mb1[i];
  for (int i = tid; i < 512; i += 1024) sh.fb1[i] = P.fb1[i];
  if (tid < 128) {
    sh.mb2[tid]  = P.mb2[tid];  sh.fb2[tid]  = P.fb2[tid];
    sh.lnsw[tid] = P.lnsw[tid]; sh.lnsb[tid] = P.lnsb[tid];
    sh.lnmw[tid] = P.lnmw[tid]; sh.lnmb[tid] = P.lnmb[tid];
    sh.pl1w[tid] = P.pl1w[tid]; sh.pl1b[tid] = P.pl1b[tid];
    sh.pl2w[tid] = P.pl2w[tid]; sh.pl2b[tid] = P.pl2b[tid];
    sh.plfw[tid] = P.plfw[tid]; sh.plfb[tid] = P.plfb[tid];
  }
  {
    int kk = tid >> 7, s = tid & 127;
    sh.slots[kk][s] = P.mu[s] + expf(P.lsig[s]) * P.noise[(b * 8 + kk) * 128 + s];
  }
  __syncthreads();

  for (int t = 0; t < 12; t++) {
    const _Float16* kt = P.kbuf + ((size_t)(b * 12 + t)) * 1024 * 128 + (size_t)n0 * 128;
    const _Float16* vt = P.vT   + ((size_t)(b * 12 + t)) * 128 * 1024 + n0;
    // ---- stage k~/v slice into LDS (32 KB each)
    {
      int r = tid >> 4, c8 = (tid & 15) * 8;
      #pragma unroll
      for (int p = 0; p < 2; p++) {
        int row = p * 64 + r;
        *(half8*)&sh.k_lds[row][c8] = *(const half8*)(kt + (size_t)row * 128 + c8);
        *(half8*)&sh.v_lds[row][c8] = *(const half8*)(vt + (size_t)row * 1024 + c8);
      }
    }
    if (tid < 128) sh.vsum[tid] = 0.f;
    __syncthreads();
    // ---- vsum partial over local n from v_lds
    {
      int s = tid >> 3, j = tid & 7;
      float a = 0.f;
      #pragma unroll
      for (int e = 0; e < 16; e++) a += (float)sh.v_lds[s][j * 16 + e];
      atomicAdd(&sh.vsum[s], a);
    }
    __syncthreads();
    if (tid < 128)
      __hip_atomic_store(&P.vs_p[(b * 8 + g) * 128 + tid], sh.vsum[tid],
                         __ATOMIC_RELAXED, __HIP_MEMORY_SCOPE_AGENT);

    for (int it = 0; it < 3; it++) {
      const int par = (t * 3 + it) & 1;
      float* updg = P.upd_p + ((size_t)(par * 16 + b) * 8 + g) * 1024;
      float* colg = P.col_p + ((size_t)(par * 16 + b) * 8 + g) * 64;
      // ---- ph1: LN(slots) -> a16 rows 0..7 (rows 8..15 zero); h16 = f16(slots)
      if (w < 8) {
        float x0 = sh.slots[w][lane], x1 = sh.slots[w][lane + 64];
        sh.h16[w][lane] = (_Float16)x0; sh.h16[w][lane + 64] = (_Float16)x1;
        float s = x0 + x1, sq = x0 * x0 + x1 * x1;
        #pragma unroll
        for (int m = 1; m < 64; m <<= 1) { s += __shfl_xor(s, m); sq += __shfl_xor(sq, m); }
        float mn = s * 0.0078125f;
        float vr = sq * 0.0078125f - mn * mn;
        float rs = rsqrtf(vr + 1e-5f);
        sh.a16[w][lane]      = (_Float16)((x0 - mn) * rs * sh.lnsw[lane]      + sh.lnsb[lane]);
        sh.a16[w][lane + 64] = (_Float16)((x1 - mn) * rs * sh.lnsw[lane + 64] + sh.lnsb[lane + 64]);
      } else {
        sh.h16[w][lane] = (_Float16)0.f; sh.h16[w][lane + 64] = (_Float16)0.f;
        sh.a16[w][lane] = (_Float16)0.f; sh.a16[w][lane + 64] = (_Float16)0.f;
      }
      if (tid < 8) sh.colsum[tid] = 0.f;
      __syncthreads();
      // ---- ph2: w<8: logits = k~ @ y^T, softmax, colsum; w>=8: gh tiles 0,1
      if (w < 8) {
        int nloc0 = w * 16;
        floatx4 acc = (floatx4){0.f, 0.f, 0.f, 0.f};
        const _Float16* ar = &sh.k_lds[nloc0 + l15][quad * 8];
        const _Float16* br = &sh.a16[l15][quad * 8];
        #pragma unroll
        for (int ks = 0; ks < 4; ks++)
          acc = MFMA_F16(*(const half8*)(ar + ks * 32), *(const half8*)(br + ks * 32), acc);
        float cs = 0.f;
        #pragma unroll
        for (int r = 0; r < 4; r++) {
          float v = (l15 < 8) ? acc[r] : -3.0e38f;
          float mx = v;
          mx = fmaxf(mx, __shfl_xor(mx, 1, 16));
          mx = fmaxf(mx, __shfl_xor(mx, 2, 16));
          mx = fmaxf(mx, __shfl_xor(mx, 4, 16));
          mx = fmaxf(mx, __shfl_xor(mx, 8, 16));
          float pv = (l15 < 8) ? expf(v - mx) : 0.f;
          float ss = pv;
          ss += __shfl_xor(ss, 1, 16); ss += __shfl_xor(ss, 2, 16);
          ss += __shfl_xor(ss, 4, 16); ss += __shfl_xor(ss, 8, 16);
          float pn = pv / ss;
          cs += pn;
          int nloc = nloc0 + quad * 4 + r;
          sh.u.sa.attnT[l15][nloc] = (_Float16)pn;
          if (it == 2 && l15 < 8)
            P.out_attn[((size_t)(b * 12 + t) * 1024 + n0 + nloc) * 8 + l15] = pn;
        }
        cs += __shfl_xor(cs, 16); cs += __shfl_xor(cs, 32);
        if (lane < 8) atomicAdd(&sh.colsum[lane], cs);
      } else {
        const int idx8 = w - 8;
        const _Float16* ar = &sh.h16[l15][quad * 8];
        #pragma unroll
        for (int tt = 0; tt < 2; tt++) {
          int ct = idx8 + tt * 8;
          const _Float16* Bg = P.Whh + (size_t)(ct * 16 + l15) * 128 + quad * 8;
          floatx4 acc = (floatx4){0.f, 0.f, 0.f, 0.f};
          #pragma unroll
          for (int ks = 0; ks < 4; ks++)
            acc = MFMA_F16(*(const half8*)(ar + ks * 32), *(const half8*)(Bg + ks * 32), acc);
          int col = ct * 16 + l15;
          #pragma unroll
          for (int r = 0; r < 4; r++) {
            int slot = quad * 4 + r;
            if (slot < 8) sh.gh[slot][col] = acc[r] + sh.bhh[col];
          }
        }
      }
      __syncthreads();
      // ---- ph3: w<8: partial updates = P^T @ v -> global; w>=8: gh tile 2
      if (w < 8) {
        floatx4 acc = (floatx4){0.f, 0.f, 0.f, 0.f};
        const _Float16* ar = &sh.u.sa.attnT[l15][quad * 8];
        const _Float16* br = &sh.v_lds[w * 16 + l15][quad * 8];
        #pragma unroll
        for (int ks = 0; ks < 4; ks++)
          acc = MFMA_F16(*(const half8*)(ar + ks * 32), *(const half8*)(br + ks * 32), acc);
        int scol = w * 16 + l15;
        #pragma unroll
        for (int r = 0; r < 4; r++) {
          int slot = quad * 4 + r;
          if (slot < 8)
            __hip_atomic_store(&updg[slot * 128 + scol], acc[r],
                               __ATOMIC_RELAXED, __HIP_MEMORY_SCOPE_AGENT);
        }
      } else {
        const int idx8 = w - 8;
        int ct = idx8 + 16;
        const _Float16* ar = &sh.h16[l15][quad * 8];
        const _Float16* Bg = P.Whh + (size_t)(ct * 16 + l15) * 128 + quad * 8;
        floatx4 acc = (floatx4){0.f, 0.f, 0.f, 0.f};
        #pragma unroll
        for (int ks = 0; ks < 4; ks++)
          acc = MFMA_F16(*(const half8*)(ar + ks * 32), *(const half8*)(Bg + ks * 32), acc);
        int col = ct * 16 + l15;
        #pragma unroll
        for (int r = 0; r < 4; r++) {
          int slot = quad * 4 + r;
          if (slot < 8) sh.gh[slot][col] = acc[r] + sh.bhh[col];
        }
      }
      if (tid < 8)
        __hip_atomic_store(&colg[tid], sh.colsum[tid],
                           __ATOMIC_RELAXED, __HIP_MEMORY_SCOPE_AGENT);
      // ---- 8-block barrier (padded counter)
      bar_phase++;
      group_barrier(ctrb, 8 * bar_phase);
      // ---- reduce partials (self-computed csum/vsum; no internal syncs)
      {
        int slot = tid >> 7, scol = tid & 127;
        const float* up = P.upd_p + (size_t)(par * 16 + b) * 8 * 1024 + slot * 128 + scol;
        float sum = 0.f;
        #pragma unroll
        for (int gg = 0; gg < 8; gg++)
          sum += __hip_atomic_load((float*)(up + gg * 1024),
                                   __ATOMIC_RELAXED, __HIP_MEMORY_SCOPE_AGENT);
        const float* cp = P.col_p + (size_t)(par * 16 + b) * 8 * 64 + slot;
        float csum = 0.f;
        #pragma unroll
        for (int gg = 0; gg < 8; gg++)
          csum += __hip_atomic_load((float*)(cp + gg * 64),
                                    __ATOMIC_RELAXED, __HIP_MEMORY_SCOPE_AGENT);
        float vsv;
        if (it == 0) {
          const float* vp = P.vs_p + b * 8 * 128 + scol;
          float vtot = 0.f;
          #pragma unroll
          for (int gg = 0; gg < 8; gg++)
            vtot += __hip_atomic_load((float*)(vp + gg * 128),
                                      __ATOMIC_RELAXED, __HIP_MEMORY_SCOPE_AGENT);
          if (slot == 0) sh.vsum[scol] = vtot;
          vsv = vtot;
        } else {
          vsv = sh.vsum[scol];
        }
        float upd = (sum + 1e-8f * vsv) / (csum + 1024.f * 1e-8f);
        sh.a16[slot][scol] = (_Float16)upd;
      }
      __syncthreads();
      // ---- GRU gi: all waves tile ct=w; w<8 also ct=16+w
      {
        const _Float16* ar = &sh.a16[l15][quad * 8];
        const _Float16* Bg = P.Wih + (size_t)(w * 16 + l15) * 128 + quad * 8;
        floatx4 acc = (floatx4){0.f, 0.f, 0.f, 0.f};
        #pragma unroll
        for (int ks = 0; ks < 4; ks++)
          acc = MFMA_F16(*(const half8*)(ar + ks * 32), *(const half8*)(Bg + ks * 32), acc);
        int col = w * 16 + l15;
        #pragma unroll
        for (int r = 0; r < 4; r++) {
          int slot = quad * 4 + r;
          if (slot < 8) sh.gi[slot][col] = acc[r] + sh.bih[col];
        }
        if (w < 8) {
          int col2 = (16 + w) * 16 + l15;
          const _Float16* Bg2 = P.Wih + (size_t)((16 + w) * 16 + l15) * 128 + quad * 8;
          floatx4 acc2 = (floatx4){0.f, 0.f, 0.f, 0.f};
          #pragma unroll
          for (int ks = 0; ks < 4; ks++)
            acc2 = MFMA_F16(*(const half8*)(ar + ks * 32), *(const half8*)(Bg2 + ks * 32), acc2);
          #pragma unroll
          for (int r = 0; r < 4; r++) {
            int slot = quad * 4 + r;
            if (slot < 8) sh.gi[slot][col2] = acc2[r] + sh.bih[col2];
          }
        }
      }
      __syncthreads();
      // ---- gates + LN fused (waves 0-7); writes slots + a16 (lnm / pl1)
      if (w < 8) {
        float h0 = sh.slots[w][lane], h1 = sh.slots[w][lane + 64];
        float r0 = 1.f / (1.f + expf(-(sh.gi[w][lane]       + sh.gh[w][lane])));
        float z0 = 1.f / (1.f + expf(-(sh.gi[w][128 + lane] + sh.gh[w][128 + lane])));
        float n0v = tanhf(sh.gi[w][256 + lane] + r0 * sh.gh[w][256 + lane]);
        float x0 = (1.f - z0) * n0v + z0 * h0;
        int l64 = lane + 64;
        float r1 = 1.f / (1.f + expf(-(sh.gi[w][l64]       + sh.gh[w][l64])));
        float z1 = 1.f / (1.f + expf(-(sh.gi[w][128 + l64] + sh.gh[w][128 + l64])));
        float n1v = tanhf(sh.gi[w][256 + l64] + r1 * sh.gh[w][256 + l64]);
        float x1 = (1.f - z1) * n1v + z1 * h1;
        sh.slots[w][lane] = x0; sh.slots[w][lane + 64] = x1;
        if (it == 2 && g == 0) {
          P.out_slots[((size_t)(b * 12 + t) * 8 + w) * 128 + lane]      = x0;
          P.out_slots[((size_t)(b * 12 + t) * 8 + w) * 128 + lane + 64] = x1;
        }
        const float* wv = (it < 2) ? sh.lnmw : sh.pl1w;
        const float* bv = (it < 2) ? sh.lnmb : sh.pl1b;
        float s = x0 + x1, sq = x0 * x0 + x1 * x1;
        #pragma unroll
        for (int m = 1; m < 64; m <<= 1) { s += __shfl_xor(s, m); sq += __shfl_xor(sq, m); }
        float mn = s * 0.0078125f;
        float vr = sq * 0.0078125f - mn * mn;
        float rs = rsqrtf(vr + 1e-5f);
        sh.a16[w][lane]      = (_Float16)((x0 - mn) * rs * wv[lane]      + bv[lane]);
        sh.a16[w][lane + 64] = (_Float16)((x1 - mn) * rs * wv[lane + 64] + bv[lane + 64]);
      }
      __syncthreads();
      // ---- residual MLP (iters 0,1)
      if (it < 2) {
        {
          floatx4 acc = (floatx4){0.f, 0.f, 0.f, 0.f};
          const _Float16* ar = &sh.a16[l15][quad * 8];
          const _Float16* br = P.W1T + (size_t)(w * 16 + l15) * 128 + quad * 8;
          #pragma unroll
          for (int ks = 0; ks < 4; ks++)
            acc = MFMA_F16(*(const half8*)(ar + ks * 32), *(const half8*)(br + ks * 32), acc);
          int col = w * 16 + l15;
          #pragma unroll
          for (int r = 0; r < 4; r++) {
            int slot = quad * 4 + r;
            if (slot < 8) sh.u.mlp.m16[slot][col] = (_Float16)fmaxf(acc[r] + sh.mb1[col], 0.f);
            else          sh.u.mlp.m16[slot][col] = (_Float16)0.f;
          }
        }
        __syncthreads();
        if (w < 8) {
          floatx4 acc = (floatx4){0.f, 0.f, 0.f, 0.f};
          const _Float16* ar = &sh.u.mlp.m16[l15][quad * 8];
          const _Float16* br = P.W2T + (size_t)(w * 16 + l15) * 256 + quad * 8;
          #pragma unroll
          for (int ks = 0; ks < 8; ks++)
            acc = MFMA_F16(*(const half8*)(ar + ks * 32), *(const half8*)(br + ks * 32), acc);
          int col = w * 16 + l15;
          #pragma unroll
          for (int r = 0; r < 4; r++) {
            int slot = quad * 4 + r;
            if (slot < 8) sh.slots[slot][col] += acc[r] + sh.mb2[col];
          }
        }
        __syncthreads();
      }
    } // it

    // ---- predictor (redundant, identical in all 8 blocks); a16 = LN_pl1(slots)
    {
      const _Float16* ar = &sh.a16[l15][quad * 8];
      int gg = w >> 3, ct = w & 7, col = ct * 16 + l15;
      const _Float16* Bg = (gg == 0 ? P.pQT : P.pKT) + (size_t)(ct * 16 + l15) * 128 + quad * 8;
      floatx4 acc = (floatx4){0.f, 0.f, 0.f, 0.f};
      #pragma unroll
      for (int ks = 0; ks < 4; ks++)
        acc = MFMA_F16(*(const half8*)(ar + ks * 32), *(const half8*)(Bg + ks * 32), acc);
      float scale = (gg == 0) ? 0.17677669529663687f : 1.f;
      float* dst = (gg == 0) ? &sh.u.mha.qh[0][0] : &sh.u.mha.kh[0][0];
      #pragma unroll
      for (int r = 0; r < 4; r++) {
        int slot = quad * 4 + r;
        if (slot < 8) dst[slot * 128 + col] = acc[r] * scale;
      }
      if (w < 8) {
        const _Float16* Bg2 = P.pVT + (size_t)(w * 16 + l15) * 128 + quad * 8;
        floatx4 a2 = (floatx4){0.f, 0.f, 0.f, 0.f};
        #pragma unroll
        for (int ks = 0; ks < 4; ks++)
          a2 = MFMA_F16(*(const half8*)(ar + ks * 32), *(const half8*)(Bg2 + ks * 32), a2);
        int colv = w * 16 + l15;
        #pragma unroll
        for (int r = 0; r < 4; r++) {
          int slot = quad * 4 + r;
          if (slot < 8) sh.u.mha.vh[slot][colv] = a2[r];
        }
      }
    }
    __syncthreads();
    // ---- fused mha: scores + softmax + P@V, one wave per head (w<4)
    if (w < 4) {
      int h = w, a = lane >> 3, b2 = lane & 7;
      const float* qr = &sh.u.mha.qh[a][h * 32];
      const float* kr = &sh.u.mha.kh[b2][h * 32];
      float s = 0.f;
      #pragma unroll
      for (int d = 0; d < 32; d++) s += qr[d] * kr[d];
      float mx = s;
      mx = fmaxf(mx, __shfl_xor(mx, 1, 8));
      mx = fmaxf(mx, __shfl_xor(mx, 2, 8));
      mx = fmaxf(mx, __shfl_xor(mx, 4, 8));
      float e = expf(s - mx);
      float ssum = e;
      ssum += __shfl_xor(ssum, 1, 8); ssum += __shfl_xor(ssum, 2, 8); ssum += __shfl_xor(ssum, 4, 8);
      float p = e / ssum;
      float o0 = 0.f, o1 = 0.f, o2 = 0.f, o3 = 0.f;
      int d0 = h * 32 + b2 * 4;
      #pragma unroll
      for (int j = 0; j < 8; j++) {
        float pj = __shfl(p, (a << 3) + j);
        const float* vr = &sh.u.mha.vh[j][d0];
        o0 += pj * vr[0]; o1 += pj * vr[1]; o2 += pj * vr[2]; o3 += pj * vr[3];
      }
      sh.a16[a][d0]     = (_Float16)o0;
      sh.a16[a][d0 + 1] = (_Float16)o1;
      sh.a16[a][d0 + 2] = (_Float16)o2;
      sh.a16[a][d0 + 3] = (_Float16)o3;
    }
    __syncthreads();
    if (w < 8) {       // s += o @ Wo
      floatx4 acc = (floatx4){0.f, 0.f, 0.f, 0.f};
      const _Float16* ar = &sh.a16[l15][quad * 8];
      const _Float16* br = P.pOT + (size_t)(w * 16 + l15) * 128 + quad * 8;
      #pragma unroll
      for (int ks = 0; ks < 4; ks++)
        acc = MFMA_F16(*(const half8*)(ar + ks * 32), *(const half8*)(br + ks * 32), acc);
      int col = w * 16 + l15;
      #pragma unroll
      for (int r = 0; r < 4; r++) {
        int slot = quad * 4 + r;
        if (slot < 8) sh.slots[slot][col] += acc[r];
      }
    }
    __syncthreads();
    ln_to_a16(&sh, sh.slots, sh.pl2w, sh.pl2b, w, lane);
    __syncthreads();
    for (int ct = w; ct < 32; ct += 16) {   // FFN1 + relu
      floatx4 acc = (floatx4){0.f, 0.f, 0.f, 0.f};
      const _Float16* ar = &sh.a16[l15][quad * 8];
      const _Float16* br = P.pF1T + (size_t)(ct * 16 + l15) * 128 + quad * 8;
      #pragma unroll
      for (int ks = 0; ks < 4; ks++)
        acc = MFMA_F16(*(const half8*)(ar + ks * 32), *(const half8*)(br + ks * 32), acc);
      int col = ct * 16 + l15;
      #pragma unroll
      for (int r = 0; r < 4; r++) {
        int slot = quad * 4 + r;
        if (slot < 8) sh.u.ffn.f16[slot][col] = (_Float16)fmaxf(acc[r] + sh.fb1[col], 0.f);
        else          sh.u.ffn.f16[slot][col] = (_Float16)0.f;
      }
    }
    __syncthreads();
    if (w < 8) {       // FFN2 + residual
      floatx4 acc = (floatx4){0.f, 0.f, 0.f, 0.f};
      const _Float16* ar = &sh.u.ffn.f16[l15][quad * 8];
      const _Float16* br = P.pF2T + (size_t)(w * 16 + l15) * 512 + quad * 8;
      #pragma unroll 4
      for (int ks = 0; ks < 16; ks++)
        acc = MFMA_F16(*(const half8*)(ar + ks * 32), *(const half8*)(br + ks * 32), acc);
      int col = w * 16 + l15;
      #pragma unroll
      for (int r = 0; r < 4; r++) {
        int slot = quad * 4 + r;
        if (slot < 8) sh.slots[slot][col] += acc[r] + sh.fb2[col];
      }
    }
    __syncthreads();
    if (w < 8) {       // final LN -> carry
      float x0 = sh.slots[w][lane], x1 = sh.slots[w][lane + 64];
      float s = x0 + x1, sq = x0 * x0 + x1 * x1;
      #pragma unroll
      for (int m = 1; m < 64; m <<= 1) { s += __shfl_xor(s, m); sq += __shfl_xor(sq, m); }
      float mn = s * 0.0078125f;
      float vr = sq * 0.0078125f - mn * mn;
      float rs = rsqrtf(vr + 1e-5f);
      sh.slots[w][lane]      = (x0 - mn) * rs * sh.plfw[lane]      + sh.plfb[lane];
      sh.slots[w][lane + 64] = (x1 - mn) * rs * sh.plfw[lane + 64] + sh.plfb[lane + 64];
    }
    __syncthreads();
  } // t
}

// ---------------------------------------------------------------------------
extern "C" void kernel_launch(void* const* d_in, const int* in_sizes, int n_in,
                              void* d_out, int out_size, void* d_ws, size_t ws_size,
                              hipStream_t stream) {
  const float* inp   = (const float*)d_in[0];
  const float* noise = (const float*)d_in[1];
  const float* mu    = (const float*)d_in[2];
  const float* lsig  = (const float*)d_in[3];
  const float* lniw  = (const float*)d_in[4];
  const float* lnib  = (const float*)d_in[5];
  const float* lnsw  = (const float*)d_in[6];
  const float* lnsb  = (const float*)d_in[7];
  const float* lnmw  = (const float*)d_in[8];
  const float* lnmb  = (const float*)d_in[9];
  const float* Wq    = (const float*)d_in[10];
  const float* Wk    = (const float*)d_in[11];
  const float* Wv    = (const float*)d_in[12];
  const float* gWih  = (const float*)d_in[13];
  const float* gWhh  = (const float*)d_in[14];
  const float* gbih  = (const float*)d_in[15];
  const float* gbhh  = (const float*)d_in[16];
  const float* mW1   = (const float*)d_in[17];
  const float* mb1   = (const float*)d_in[18];
  const float* mW2   = (const float*)d_in[19];
  const float* mb2   = (const float*)d_in[20];
  const float* pl1w  = (const float*)d_in[21];
  const float* pl1b  = (const float*)d_in[22];
  const float* pWq   = (const float*)d_in[23];
  const float* pWk   = (const float*)d_in[24];
  const float* pWv   = (const float*)d_in[25];
  const float* pWo   = (const float*)d_in[26];
  const float* pl2w  = (const float*)d_in[27];
  const float* pl2b  = (const float*)d_in[28];
  const float* pf1   = (const float*)d_in[29];
  const float* pfb1  = (const float*)d_in[30];
  const float* pf2   = (const float*)d_in[31];
  const float* pfb2  = (const float*)d_in[32];
  const float* plfw  = (const float*)d_in[33];
  const float* plfb  = (const float*)d_in[34];

  // workspace layout (f16 elements)
  _Float16* p   = (_Float16*)d_ws;
  _Float16* kbuf = p;  p += 25165824;
  _Float16* vT   = p;  p += 25165824;
  _Float16* WT   = p;  p += 65536;
  _Float16* WqT  = p;  p += 16384;   // unused (k~ fold), kept for layout
  _Float16* Wih  = p;  p += 49152;
  _Float16* Whh  = p;  p += 49152;
  _Float16* W1T  = p;  p += 32768;
  _Float16* W2T  = p;  p += 32768;
  _Float16* pQT  = p;  p += 16384;
  _Float16* pKT  = p;  p += 16384;
  _Float16* pVT  = p;  p += 16384;
  _Float16* pOT  = p;  p += 16384;
  _Float16* pF1T = p;  p += 65536;
  _Float16* pF2T = p;  p += 65536;
  float* fb   = (float*)p;
  float* upd_p = fb;  fb += 2 * 16 * 8 * 1024;   // 131072
  float* col_p = fb;  fb += 2 * 16 * 8 * 64;     // 16384 (256B-padded groups)
  float* vs_p  = fb;  fb += 16 * 8 * 128;        // 16384
  int*   ctr   = (int*)fb;                       // 16 x 64 (256B-padded)
  (void)WqT;

  const float kscale = 0.08838834764831845f;  // S^-0.5, S=128
  init_ctr_kernel<<<1, 1024, 0, stream>>>(ctr);

  PrepJobs J;
  const float* srcs[11] = {Wv, gWih, gWhh, mW1, mW2, pWq, pWk, pWv, pWo, pf1, pf2};
  _Float16* dsts[11]    = {WT + 32768, Wih, Whh, W1T, W2T, pQT, pKT, pVT, pOT, pF1T, pF2T};
  int Ins[11]    = {256, 49152, 49152, 128, 256, 128, 128, 128, 128, 128, 512};
  int Outs[11]   = {128, 1, 1, 256, 128, 128, 128, 128, 128, 512, 128};
  int elemss[11] = {32768, 49152, 49152, 32768, 32768, 16384, 16384, 16384, 16384, 65536, 65536};
  int doTs[11]   = {1, 0, 0, 1, 1, 1, 1, 1, 1, 1, 1};
  float scales[11] = {1.f, 1.f, 1.f, 1.f, 1.f, 1.f, 1.f, 1.f, 1.f, 1.f, 1.f};
  for (int j = 0; j < 11; j++) {
    J.src[j] = srcs[j]; J.dst[j] = dsts[j]; J.In[j] = Ins[j]; J.Out[j] = Outs[j];
    J.elems[j] = elemss[j]; J.doT[j] = doTs[j]; J.scale[j] = scales[j];
  }
  dim3 gp(256, 11, 1);
  prep_all_kernel<<<gp, 256, 0, stream>>>(J);
  prep_wtilde_kernel<<<128, 256, 0, stream>>>(Wk, Wq, WT, kscale);

  dim3 g1(1536, 2, 1);
  gemm_kv_kernel<<<g1, 256, 0, stream>>>(inp, lniw, lnib, WT, kbuf, vT);

  P2Args a;
  a.kbuf = kbuf; a.vT = vT;
  a.Wih = Wih; a.Whh = Whh; a.W1T = W1T; a.W2T = W2T;
  a.pQT = pQT; a.pKT = pKT; a.pVT = pVT; a.pOT = pOT; a.pF1T = pF1T; a.pF2T = pF2T;
  a.noise = noise; a.mu = mu; a.lsig = lsig;
  a.lnsw = lnsw; a.lnsb = lnsb; a.lnmw = lnmw; a.lnmb = lnmb;
  a.bih = gbih; a.bhh = gbhh; a.mb1 = mb1; a.mb2 = mb2;
  a.pl1w = pl1w; a.pl1b = pl1b; a.pl2w = pl2w; a.pl2b = pl2b;
  a.fb1 = pfb1; a.fb2 = pfb2; a.plfw = plfw; a.plfb = plfb;
  a.out_slots = (float*)d_out;
  a.out_attn  = (float*)d_out + 196608;
  a.upd_p = upd_p; a.col_p = col_p; a.vs_p = vs_p; a.ctr = ctr;

  slot_attn_kernel<<<128, 1024, 0, stream>>>(a);
}